// Round 11
// baseline (4191.639 us; speedup 1.0000x reference)
//
#include <hip/hip_runtime.h>
#include <math.h>

#define N_UE 16384
#define N_AP 128
#define NE   2097152
#define CHS  16                     // src-side edges per chunk/thread
#define CHD  16                     // dst-side edges per chunk/thread
#define NEP  (NE + CHS * N_UE)      // padded src-sorted capacity 2359296
#define NCHU (NEP / CHS)            // 147456 src chunks
#define NEPD (NE + CHD * N_AP)      // padded dst-sorted capacity 2099200
#define NCHD_AL 131328              // 513*256 dst chunks (covers NEPD/CHD)
#define SRC_BLKS (NCHU / 256)       // 576
#define DST_BLKS (NCHD_AL / 256)    // 513

#define RFL(x) __int_as_float(__builtin_amdgcn_readfirstlane(__float_as_int(x)))

// ---------------------------------------------------------------------------
// prefill: sentinels in padded index arrays, chunk maps, zero histograms
// ---------------------------------------------------------------------------
__global__ __launch_bounds__(256) void prefill(
    int* __restrict__ dtS, int* __restrict__ srcD,
    int* __restrict__ cnS, int* __restrict__ cnD,
    int* __restrict__ cnt, int* __restrict__ cntD)
{
    int i = blockIdx.x * 256 + threadIdx.x;    // grid = NEP/256
    dtS[i] = N_AP;                             // sentinel AP row (-1e30)
    if (i < NEPD) srcD[i] = N_UE;              // sentinel UE row (-1e30)
    if (i < NCHU) cnS[i] = -1;
    if (i < NCHD_AL) cnD[i] = -1;
    if (i < N_UE) cnt[i] = 0;
    if (i < N_AP) cntD[i] = 0;
}

// ---------------------------------------------------------------------------
// init tables + sentinel rows
// ---------------------------------------------------------------------------
__global__ __launch_bounds__(256) void init_kernel(
    const float* __restrict__ x_ue, const float* __restrict__ Wm1_ua,
    const float* __restrict__ bm1_ua, const float* __restrict__ bm1_au,
    float* __restrict__ Qua, float* __restrict__ Pau)
{
    int i = blockIdx.x * 256 + threadIdx.x;
    int d = i & 31;
    Qua[i] = fmaf(x_ue[i >> 5], Wm1_ua[d], bm1_ua[d]);
    if (i < N_AP * 32) Pau[i] = bm1_au[d];
    if (i < 32) { Qua[N_UE * 32 + i] = -1e30f; Pau[N_AP * 32 + i] = -1e30f; }
}

// ---------------------------------------------------------------------------
// global-atomic degree histograms (L2-resident counters)
// ---------------------------------------------------------------------------
__global__ __launch_bounds__(256) void hist_glob(
    const int* __restrict__ src, const int* __restrict__ dst,
    int* __restrict__ cnt, int* __restrict__ cntD)
{
    const int e = blockIdx.x * 256 + threadIdx.x;   // grid = NE/256
    atomicAdd(&cnt[src[e]], 1);
    atomicAdd(&cntD[dst[e]], 1);
}

// ---------------------------------------------------------------------------
// scans: chunk-aligned region starts + global cursors
// ---------------------------------------------------------------------------
__global__ __launch_bounds__(256) void scan_src(
    const int* __restrict__ cnt, int* __restrict__ CU, int* __restrict__ cursorU)
{
    __shared__ int ps[256];
    __shared__ int ps2[257];
    const int t = threadIdx.x;
    const int b0 = t * (N_UE / 256);
    int s = 0;
    for (int i = 0; i < N_UE / 256; ++i) s += (cnt[b0 + i] + CHS - 1) / CHS;
    ps[t] = s;
    __syncthreads();
    if (t == 0) {
        int r = 0;
        for (int i = 0; i < 256; ++i) { ps2[i] = r; r += ps[i]; }
        ps2[256] = r;
    }
    __syncthreads();
    int r = ps2[t];
    for (int i = 0; i < N_UE / 256; ++i) {
        CU[b0 + i] = r;
        cursorU[b0 + i] = r * CHS;
        r += (cnt[b0 + i] + CHS - 1) / CHS;
    }
    if (t == 255) CU[N_UE] = ps2[256];
}

__global__ __launch_bounds__(128) void scan_dst(
    const int* __restrict__ cntD, int* __restrict__ CA, int* __restrict__ cursorD)
{
    __shared__ int tot[N_AP];
    const int a = threadIdx.x;
    tot[a] = (cntD[a] + CHD - 1) / CHD;
    __syncthreads();
    if (a == 0) {
        int r = 0;
        for (int i = 0; i < N_AP; ++i) { CA[i] = r; r += tot[i]; }
        CA[N_AP] = r;
    }
    __syncthreads();
    cursorD[a] = CA[a] * CHD;
}

// ---------------------------------------------------------------------------
// global-atomic scatter: one thread per edge, no LDS, full occupancy.
// ---------------------------------------------------------------------------
__global__ __launch_bounds__(256) void scatter_glob(
    const int* __restrict__ src, const int* __restrict__ dst,
    const float2* __restrict__ e0ua, const float2* __restrict__ e0au,
    int* __restrict__ cursorU, int* __restrict__ cursorD,
    int* __restrict__ dtS, float2* __restrict__ attS, int* __restrict__ invS,
    int* __restrict__ srcD, float2* __restrict__ attD, int* __restrict__ invD)
{
    const int e = blockIdx.x * 256 + threadIdx.x;   // grid = NE/256
    const int s = src[e], dt = dst[e];
    const int pos = atomicAdd(&cursorU[s], 1);
    dtS[pos] = dt;
    attS[pos] = e0au[e];
    invS[e] = pos;
    const int posd = atomicAdd(&cursorD[dt], 1);
    srcD[posd] = s;
    attD[posd] = e0ua[e];
    invD[e] = posd;
}

// ---------------------------------------------------------------------------
// chunk maps
// ---------------------------------------------------------------------------
__global__ __launch_bounds__(256) void build_map_src(
    const int* __restrict__ CU, int* __restrict__ cnS)
{
    const int u = blockIdx.x * 256 + threadIdx.x;   // grid 64
    const int c0 = CU[u], c1 = CU[u + 1];
    for (int c = c0; c < c1; ++c) cnS[c] = u;
}

__global__ __launch_bounds__(128) void build_map_dst(
    const int* __restrict__ CA, int* __restrict__ cnD)
{
    const int a = threadIdx.x;
    const int c0 = CA[a], c1 = CA[a + 1];
    for (int c = c0; c < c1; ++c) cnD[c] = a;
}

// ---------------------------------------------------------------------------
// fused edge pass: blocks [0,SRC_BLKS) = src chunks; rest = dst chunks.
// src: thread = 16-edge chunk of ONE UE node -> partialU row (no atomics).
// dst: thread = 16-edge chunk of ONE AP node -> partialA row (no atomics).
// ---------------------------------------------------------------------------
template<bool EUPD>
__global__ __launch_bounds__(256) void pass_both(
    const int* __restrict__ cnS, const int* __restrict__ dtS,
    float2* __restrict__ attS,
    const int* __restrict__ cnD, const int* __restrict__ srcD,
    float2* __restrict__ attD,
    const float2* __restrict__ RueA, const float2* __restrict__ RueB,
    const float2* __restrict__ RapA, const float2* __restrict__ RapB,
    const float* __restrict__ EcA, const float* __restrict__ EcB,
    const float* __restrict__ Qua, const float* __restrict__ Pau,
    const float* __restrict__ cu, const float* __restrict__ cw,
    float* __restrict__ partialU, float* __restrict__ partialA)
{
    if (blockIdx.x < SRC_BLKS) {
        const int ch = blockIdx.x * 256 + threadIdx.x;
        const int u = cnS[ch];
        if (u < 0) return;
        float w0v[32], w1v[32];
        #pragma unroll
        for (int d = 0; d < 32; ++d) { w0v[d] = RFL(cw[d]); w1v[d] = RFL(cw[32 + d]); }
        float d00 = 0.f, d01 = 0.f, d10 = 0.f, d11 = 0.f, rbx = 0.f, rby = 0.f;
        if constexpr (EUPD) {
            d00 = RFL(EcB[0]); d01 = RFL(EcB[1]); d10 = RFL(EcB[2]); d11 = RFL(EcB[3]);
            float2 r = RueB[u]; rbx = r.x; rby = r.y;
        }
        const float4* __restrict__ Pau4 = (const float4*)Pau;
        const int base = ch * CHS;
        float4 acc[8];
        #pragma unroll
        for (int q = 0; q < 8; ++q) acc[q] = make_float4(0.f, 0.f, 0.f, 0.f);
        #pragma unroll 4
        for (int j = 0; j < CHS; ++j) {
            int dt = dtS[base + j];
            float2 a = attS[base + j];
            if constexpr (EUPD) {
                float2 rp = RapB[dt];
                float m0 = fmaxf(rbx + rp.x + a.x * d00 + a.y * d10, 0.f);
                float m1 = fmaxf(rby + rp.y + a.x * d01 + a.y * d11, 0.f);
                a = make_float2(m0, m1);
                attS[base + j] = a;
            }
            const float4* pr = Pau4 + dt * 8;
            #pragma unroll
            for (int q = 0; q < 8; ++q) {
                float4 pv = pr[q];
                acc[q].x += fmaxf(fmaf(a.x, w0v[q*4+0], fmaf(a.y, w1v[q*4+0], pv.x)), 0.f);
                acc[q].y += fmaxf(fmaf(a.x, w0v[q*4+1], fmaf(a.y, w1v[q*4+1], pv.y)), 0.f);
                acc[q].z += fmaxf(fmaf(a.x, w0v[q*4+2], fmaf(a.y, w1v[q*4+2], pv.z)), 0.f);
                acc[q].w += fmaxf(fmaf(a.x, w0v[q*4+3], fmaf(a.y, w1v[q*4+3], pv.w)), 0.f);
            }
        }
        float4* pu = (float4*)(partialU + (size_t)ch * 32);
        #pragma unroll
        for (int q = 0; q < 8; ++q) pu[q] = acc[q];
    } else {
        const int ch = (blockIdx.x - SRC_BLKS) * 256 + threadIdx.x;
        const int a = cnD[ch];
        if (a < 0) return;
        float u0v[32], u1v[32];
        #pragma unroll
        for (int d = 0; d < 32; ++d) { u0v[d] = RFL(cu[d]); u1v[d] = RFL(cu[32 + d]); }
        float c00 = 0.f, c01 = 0.f, c10 = 0.f, c11 = 0.f, rax = 0.f, ray = 0.f;
        if constexpr (EUPD) {
            c00 = RFL(EcA[0]); c01 = RFL(EcA[1]); c10 = RFL(EcA[2]); c11 = RFL(EcA[3]);
            float2 r = RapA[a]; rax = r.x; ray = r.y;
        }
        const float4* __restrict__ Qua4 = (const float4*)Qua;
        const int base = ch * CHD;
        float4 acc[8];
        #pragma unroll
        for (int q = 0; q < 8; ++q) acc[q] = make_float4(0.f, 0.f, 0.f, 0.f);
        #pragma unroll 4
        for (int j = 0; j < CHD; ++j) {
            int s = srcD[base + j];
            float2 a2 = attD[base + j];
            if constexpr (EUPD) {
                float2 ru = RueA[s];
                float n0 = fmaxf(rax + ru.x + a2.x * c00 + a2.y * c10, 0.f);
                float n1 = fmaxf(ray + ru.y + a2.x * c01 + a2.y * c11, 0.f);
                a2 = make_float2(n0, n1);
                attD[base + j] = a2;
            }
            const float4* qr = Qua4 + s * 8;
            #pragma unroll
            for (int q = 0; q < 8; ++q) {
                float4 qv = qr[q];
                acc[q].x += fmaxf(fmaf(a2.x, u0v[q*4+0], fmaf(a2.y, u1v[q*4+0], qv.x)), 0.f);
                acc[q].y += fmaxf(fmaf(a2.x, u0v[q*4+1], fmaf(a2.y, u1v[q*4+1], qv.y)), 0.f);
                acc[q].z += fmaxf(fmaf(a2.x, u0v[q*4+2], fmaf(a2.y, u1v[q*4+2], qv.z)), 0.f);
                acc[q].w += fmaxf(fmaf(a2.x, u0v[q*4+3], fmaf(a2.y, u1v[q*4+3], qv.w)), 0.f);
            }
        }
        float4* pa = (float4*)(partialA + (size_t)ch * 32);
        #pragma unroll
        for (int q = 0; q < 8; ++q) pa[q] = acc[q];
    }
}

// ---------------------------------------------------------------------------
// reduce_ue: 32-lane group per node sums its chunk partial rows.
// ---------------------------------------------------------------------------
__global__ __launch_bounds__(256) void reduce_ue(
    const int* __restrict__ CU, const float* __restrict__ partialU,
    float* __restrict__ agg_ue)
{
    const int g   = (blockIdx.x * 256 + threadIdx.x) >> 5;   // node, grid=2048
    const int dim = threadIdx.x & 31;
    const int c0 = CU[g], c1 = CU[g + 1];
    float acc = 0.f;
    for (int c = c0; c < c1; ++c) acc += partialU[(size_t)c * 32 + dim];
    agg_ue[g * 32 + dim] = acc;
}

// ---------------------------------------------------------------------------
// Final layer-4 edge update, original order.
// ---------------------------------------------------------------------------
__global__ __launch_bounds__(256) void final_edge(
    const int* __restrict__ src, const int* __restrict__ dst,
    const int* __restrict__ invS, const int* __restrict__ invD,
    const float2* __restrict__ attS, const float2* __restrict__ attD,
    const float2* __restrict__ RueA, const float2* __restrict__ RueB,
    const float2* __restrict__ RapA, const float2* __restrict__ RapB,
    const float* __restrict__ EcA, const float* __restrict__ EcB,
    float2* __restrict__ out_eua, float2* __restrict__ out_eau)
{
    const int e = blockIdx.x * 256 + threadIdx.x;
    const int s = src[e], dt = dst[e];
    float c00 = EcA[0], c01 = EcA[1], c10 = EcA[2], c11 = EcA[3];
    float d00 = EcB[0], d01 = EcB[1], d10 = EcB[2], d11 = EcB[3];
    float2 eua = attD[invD[e]];
    float2 eau = attS[invS[e]];
    float2 rA = RueA[s], pA = RapA[dt];
    float n0 = fmaxf(rA.x + pA.x + eua.x * c00 + eua.y * c10, 0.f);
    float n1 = fmaxf(rA.y + pA.y + eua.x * c01 + eua.y * c11, 0.f);
    float2 rB = RueB[s], pB = RapB[dt];
    float m0 = fmaxf(rB.x + pB.x + eau.x * d00 + eau.y * d10, 0.f);
    float m1 = fmaxf(rB.y + pB.y + eau.x * d01 + eau.y * d11, 0.f);
    out_eua[e] = make_float2(n0, n1);
    out_eau[e] = make_float2(m0, m1);
}

// ---------------------------------------------------------------------------
// UE node update + next-layer tables (+ power head for LAST). 64-thr blocks.
// ---------------------------------------------------------------------------
template<bool FIRST, bool LAST>
__global__ __launch_bounds__(64) void node_ue_kernel(
    const float* __restrict__ x_prev, const float* __restrict__ agg_ue,
    const float* __restrict__ Wu, const float* __restrict__ bu,
    const float* __restrict__ Wm_next, const float* __restrict__ bm_next,
    const float* __restrict__ WeUa, const float* __restrict__ WeUb,
    const float* __restrict__ Wp1, const float* __restrict__ bp1,
    const float* __restrict__ Wp2, const float* __restrict__ bp2,
    float* __restrict__ x_new, float* __restrict__ Qua_next,
    float2* __restrict__ RueA, float2* __restrict__ RueB,
    float2* __restrict__ ue_out)
{
    constexpr int KIN = FIRST ? 33 : 64;
    __shared__ float Wu_s[64 * 32];
    __shared__ float Wm_s[32 * 32];
    __shared__ float WeA_s[64], WeB_s[64];
    __shared__ float bu_s[32], bm_s[32];
    __shared__ float Wp1_s[32 * 16], bp1_s[16], Wp2_s[16];

    const int tid = threadIdx.x;
    for (int i = tid; i < KIN * 32; i += 64) Wu_s[i] = Wu[i];
    if (tid < 32) bu_s[tid] = bu[tid];
    if (!LAST) {
        for (int i = tid; i < 1024; i += 64) Wm_s[i] = Wm_next[i];
        if (tid < 32) bm_s[tid] = bm_next[tid];
    }
    { WeA_s[tid] = WeUa[tid]; WeB_s[tid] = WeUb[tid]; }
    if (LAST) {
        for (int i = tid; i < 512; i += 64) Wp1_s[i] = Wp1[i];
        if (tid < 16) { bp1_s[tid] = bp1[tid]; Wp2_s[tid] = Wp2[tid]; }
    }
    __syncthreads();

    const int u = blockIdx.x * 64 + tid;
    float in[KIN];
    if (FIRST) {
        in[0] = x_prev[u];
        #pragma unroll
        for (int k = 0; k < 32; ++k) in[1 + k] = agg_ue[u * 32 + k];
    } else {
        #pragma unroll
        for (int k = 0; k < 32; ++k) in[k] = x_prev[u * 32 + k];
        #pragma unroll
        for (int k = 0; k < 32; ++k) in[32 + k] = agg_ue[u * 32 + k];
    }
    float out[32];
    #pragma unroll
    for (int d = 0; d < 32; ++d) {
        float acc = bu_s[d];
        #pragma unroll
        for (int k = 0; k < KIN; ++k) acc = fmaf(in[k], Wu_s[k * 32 + d], acc);
        out[d] = fmaxf(acc, 0.f);
    }
    #pragma unroll
    for (int d = 0; d < 32; ++d) x_new[u * 32 + d] = out[d];
    if (!LAST) {
        #pragma unroll
        for (int d = 0; d < 32; ++d) {
            float acc = bm_s[d];
            #pragma unroll
            for (int k = 0; k < 32; ++k) acc = fmaf(out[k], Wm_s[k * 32 + d], acc);
            Qua_next[u * 32 + d] = acc;
        }
    }
    float r0 = 0.f, r1 = 0.f, s0 = 0.f, s1 = 0.f;
    #pragma unroll
    for (int k = 0; k < 32; ++k) {
        r0 = fmaf(out[k], WeA_s[k * 2],     r0);
        r1 = fmaf(out[k], WeA_s[k * 2 + 1], r1);
        s0 = fmaf(out[k], WeB_s[k * 2],     s0);
        s1 = fmaf(out[k], WeB_s[k * 2 + 1], s1);
    }
    RueA[u] = make_float2(r0, r1);
    RueB[u] = make_float2(s0, s1);
    if (LAST) {
        float z = bp2[0];
        #pragma unroll
        for (int j = 0; j < 16; ++j) {
            float h = bp1_s[j];
            #pragma unroll
            for (int k = 0; k < 32; ++k) h = fmaf(out[k], Wp1_s[k * 16 + j], h);
            z = fmaf(fmaxf(h, 0.f), Wp2_s[j], z);
        }
        float pw = 1.f / (1.f + expf(-z));
        ue_out[u] = make_float2(out[0], pw);
    }
}

// ---------------------------------------------------------------------------
// AP: reduce chunk partials (CA ranges) -> agg_ap, node update, tables
// ---------------------------------------------------------------------------
template<bool FIRST, bool LAST>
__global__ __launch_bounds__(256) void node_ap_kernel(
    const float* __restrict__ partialA, const int* __restrict__ CA,
    const float* __restrict__ x_prev,
    const float* __restrict__ Wu, const float* __restrict__ bu,
    const float* __restrict__ Wm_next, const float* __restrict__ bm_next,
    const float* __restrict__ WeA, const float* __restrict__ beA,
    const float* __restrict__ WeB, const float* __restrict__ beB,
    float* __restrict__ x_new, float* __restrict__ Pau_next,
    float2* __restrict__ RapA, float2* __restrict__ RapB)
{
    __shared__ float red[256];
    __shared__ float agg_s[32];
    __shared__ float xnew_s[32];
    const int a = blockIdx.x, tid = threadIdx.x;
    const int d = tid & 31, p0 = tid >> 5;
    const int c0 = CA[a], c1 = CA[a + 1];
    float acc = 0.f;
    for (int p = c0 + p0; p < c1; p += 8)
        acc += partialA[(size_t)p * 32 + d];
    red[tid] = acc;
    __syncthreads();
    if (tid < 32) {
        float s = 0.f;
        #pragma unroll
        for (int i = 0; i < 8; ++i) s += red[i * 32 + tid];
        agg_s[tid] = s;
    }
    __syncthreads();
    if (tid < 32) {
        float acc2 = bu[d];
        if (FIRST) {
            #pragma unroll
            for (int k = 0; k < 32; ++k) acc2 = fmaf(agg_s[k], Wu[k * 32 + d], acc2);
        } else {
            #pragma unroll
            for (int k = 0; k < 32; ++k) acc2 = fmaf(x_prev[a * 32 + k], Wu[k * 32 + d], acc2);
            #pragma unroll
            for (int k = 0; k < 32; ++k) acc2 = fmaf(agg_s[k], Wu[(32 + k) * 32 + d], acc2);
        }
        float xn = fmaxf(acc2, 0.f);
        xnew_s[d] = xn;
        x_new[a * 32 + d] = xn;
    }
    __syncthreads();
    if (!LAST) {
        if (tid < 32) {
            float acc3 = bm_next[d];
            #pragma unroll
            for (int k = 0; k < 32; ++k) acc3 = fmaf(xnew_s[k], Wm_next[k * 32 + d], acc3);
            Pau_next[a * 32 + d] = acc3;
        }
    }
    if (tid == 0) {
        float q0 = beA[0], q1 = beA[1], t0 = beB[0], t1 = beB[1];
        #pragma unroll
        for (int k = 0; k < 32; ++k) {
            q0 = fmaf(xnew_s[k], WeA[k * 2],     q0);
            q1 = fmaf(xnew_s[k], WeA[k * 2 + 1], q1);
            t0 = fmaf(xnew_s[k], WeB[k * 2],     t0);
            t1 = fmaf(xnew_s[k], WeB[k * 2 + 1], t1);
        }
        RapA[a] = make_float2(q0, q1);
        RapB[a] = make_float2(t0, t1);
    }
}

// ---------------------------------------------------------------------------
extern "C" void kernel_launch(void* const* d_in, const int* in_sizes, int n_in,
                              void* d_out_v, int out_size, void* d_ws, size_t ws_size,
                              hipStream_t stream)
{
    const float*  x_ue   = (const float*)d_in[0];
    const float2* e0ua   = (const float2*)d_in[1];
    const float2* e0au   = (const float2*)d_in[2];
    const int*    src    = (const int*)d_in[3];
    const int*    dst    = (const int*)d_in[4];
    const float* Wm1_ua = (const float*)d_in[5];
    const float* bm1_ua = (const float*)d_in[6];
    const float* Wm1_au = (const float*)d_in[7];
    const float* bm1_au = (const float*)d_in[8];
    const float* Wu1_ap = (const float*)d_in[9];
    const float* bu1_ap = (const float*)d_in[10];
    const float* Wu1_ue = (const float*)d_in[11];
    const float* bu1_ue = (const float*)d_in[12];
    const float* We1_ua = (const float*)d_in[13];
    const float* be1_ua = (const float*)d_in[14];
    const float* We1_au = (const float*)d_in[15];
    const float* be1_au = (const float*)d_in[16];
    const float* Wm_ua  = (const float*)d_in[17];
    const float* bm_ua  = (const float*)d_in[18];
    const float* Wm_au  = (const float*)d_in[19];
    const float* bm_au  = (const float*)d_in[20];
    const float* Wu_ap  = (const float*)d_in[21];
    const float* bu_ap  = (const float*)d_in[22];
    const float* Wu_ue  = (const float*)d_in[23];
    const float* bu_ue  = (const float*)d_in[24];
    const float* We_ua  = (const float*)d_in[25];
    const float* be_ua  = (const float*)d_in[26];
    const float* We_au  = (const float*)d_in[27];
    const float* be_au  = (const float*)d_in[28];
    const float* Wp1    = (const float*)d_in[29];
    const float* bp1    = (const float*)d_in[30];
    const float* Wp2    = (const float*)d_in[31];
    const float* bp2    = (const float*)d_in[32];

    float*  outp    = (float*)d_out_v;
    float2* out_ue  = (float2*)outp;                              // [16384][2]
    float*  out_ap  = outp + N_UE * 2;                            // [128][32]
    float2* out_eua = (float2*)(outp + N_UE * 2 + N_AP * 32);     // [E][2]
    float2* out_eau = (float2*)(outp + N_UE * 2 + N_AP * 32 + (size_t)NE * 2);

    float* ws = (float*)d_ws;
    float* x_ueA  = ws;          ws += N_UE * 32;
    float* x_ueB  = ws;          ws += N_UE * 32;
    float* x_apA  = ws;          ws += N_AP * 32;
    float* x_apB  = ws;          ws += N_AP * 32;
    float* agg_ue = ws;          ws += N_UE * 32;
    float* Qua    = ws;          ws += (N_UE + 1) * 32;
    float* Pau    = ws;          ws += (N_AP + 1) * 32;
    float2* RueA  = (float2*)ws; ws += (N_UE + 2) * 2;
    float2* RueB  = (float2*)ws; ws += (N_UE + 2) * 2;
    float2* RapA  = (float2*)ws; ws += (N_AP + 2) * 2;
    float2* RapB  = (float2*)ws; ws += (N_AP + 2) * 2;
    int* cnt     = (int*)ws;     ws += N_UE;
    int* cntD    = (int*)ws;     ws += N_AP;
    int* CU      = (int*)ws;     ws += N_UE + 4;
    int* CA      = (int*)ws;     ws += N_AP + 4;
    int* cursorU = (int*)ws;     ws += N_UE;
    int* cursorD = (int*)ws;     ws += N_AP;
    int* cnS     = (int*)ws;     ws += NCHU;
    int* cnD     = (int*)ws;     ws += NCHD_AL;
    int* invS    = (int*)ws;     ws += NE;
    int* invD    = (int*)ws;     ws += NE;
    int* dtS     = (int*)ws;     ws += NEP;
    int* srcD    = (int*)ws;     ws += NEPD;
    float2* attS = (float2*)ws;  ws += (size_t)NEP * 2;
    float2* attD = (float2*)ws;  ws += (size_t)NEPD * 2;
    float* partialU = ws;        ws += (size_t)NCHU * 32;         // 18.9 MB
    float* partialA = ws;        ws += (size_t)NCHD_AL * 32;      // 16.8 MB

    dim3 blk(256);

    // ---- sort structure (global-atomic cursors, no LDS histograms) ----
    prefill<<<NEP / 256, blk, 0, stream>>>(dtS, srcD, cnS, cnD, cnt, cntD);
    hist_glob<<<NE / 256, blk, 0, stream>>>(src, dst, cnt, cntD);
    scan_src<<<1, blk, 0, stream>>>(cnt, CU, cursorU);
    scan_dst<<<1, dim3(128), 0, stream>>>(cntD, CA, cursorD);
    scatter_glob<<<NE / 256, blk, 0, stream>>>(src, dst, e0ua, e0au,
                                               cursorU, cursorD,
                                               dtS, attS, invS, srcD, attD, invD);
    build_map_src<<<N_UE / 256, blk, 0, stream>>>(CU, cnS);
    build_map_dst<<<1, dim3(128), 0, stream>>>(CA, cnD);

    init_kernel<<<N_UE * 32 / 256, blk, 0, stream>>>(x_ue, Wm1_ua, bm1_ua, bm1_au, Qua, Pau);

    const int PB = SRC_BLKS + DST_BLKS;

    // ---- layer 1 ----
    pass_both<false><<<PB, blk, 0, stream>>>(
        cnS, dtS, attS, cnD, srcD, attD,
        nullptr, nullptr, nullptr, nullptr, nullptr, nullptr,
        Qua, Pau, Wm1_ua + 32, Wm1_au, partialU, partialA);
    reduce_ue<<<N_UE * 32 / 256, blk, 0, stream>>>(CU, partialU, agg_ue);
    node_ue_kernel<true, false><<<N_UE / 64, dim3(64), 0, stream>>>(
        x_ue, agg_ue, Wu1_ue, bu1_ue, Wm_ua, bm_ua, We1_ua, We1_au,
        nullptr, nullptr, nullptr, nullptr,
        x_ueA, Qua, RueA, RueB, nullptr);
    node_ap_kernel<true, false><<<N_AP, blk, 0, stream>>>(
        partialA, CA, nullptr, Wu1_ap, bu1_ap, Wm_au, bm_au,
        We1_ua + 64, be1_ua, We1_au + 64, be1_au,
        x_apA, Pau, RapA, RapB);

    // ---- layer 2 (edge-update 1 fused) ----
    pass_both<true><<<PB, blk, 0, stream>>>(
        cnS, dtS, attS, cnD, srcD, attD,
        RueA, RueB, RapA, RapB, We1_ua + 128, We1_au + 128,
        Qua, Pau, Wm_ua + 1024, Wm_au + 1024, partialU, partialA);
    reduce_ue<<<N_UE * 32 / 256, blk, 0, stream>>>(CU, partialU, agg_ue);
    node_ue_kernel<false, false><<<N_UE / 64, dim3(64), 0, stream>>>(
        x_ueA, agg_ue, Wu_ue, bu_ue, Wm_ua + 1088, bm_ua + 32, We_ua, We_au,
        nullptr, nullptr, nullptr, nullptr,
        x_ueB, Qua, RueA, RueB, nullptr);
    node_ap_kernel<false, false><<<N_AP, blk, 0, stream>>>(
        partialA, CA, x_apA, Wu_ap, bu_ap, Wm_au + 1088, bm_au + 32,
        We_ua + 64, be_ua, We_au + 64, be_au,
        x_apB, Pau, RapA, RapB);

    // ---- layer 3 (edge-update 2 fused) ----
    pass_both<true><<<PB, blk, 0, stream>>>(
        cnS, dtS, attS, cnD, srcD, attD,
        RueA, RueB, RapA, RapB, We_ua + 128, We_au + 128,
        Qua, Pau, Wm_ua + 2112, Wm_au + 2112, partialU, partialA);
    reduce_ue<<<N_UE * 32 / 256, blk, 0, stream>>>(CU, partialU, agg_ue);
    node_ue_kernel<false, false><<<N_UE / 64, dim3(64), 0, stream>>>(
        x_ueB, agg_ue, Wu_ue + 2048, bu_ue + 32, Wm_ua + 2176, bm_ua + 64,
        We_ua + 132, We_au + 132,
        nullptr, nullptr, nullptr, nullptr,
        x_ueA, Qua, RueA, RueB, nullptr);
    node_ap_kernel<false, false><<<N_AP, blk, 0, stream>>>(
        partialA, CA, x_apB, Wu_ap + 2048, bu_ap + 32, Wm_au + 2176, bm_au + 64,
        We_ua + 196, be_ua + 2, We_au + 196, be_au + 2,
        x_apA, Pau, RapA, RapB);

    // ---- layer 4 (edge-update 3 fused) ----
    pass_both<true><<<PB, blk, 0, stream>>>(
        cnS, dtS, attS, cnD, srcD, attD,
        RueA, RueB, RapA, RapB, We_ua + 260, We_au + 260,
        Qua, Pau, Wm_ua + 3200, Wm_au + 3200, partialU, partialA);
    reduce_ue<<<N_UE * 32 / 256, blk, 0, stream>>>(CU, partialU, agg_ue);
    node_ue_kernel<false, true><<<N_UE / 64, dim3(64), 0, stream>>>(
        x_ueA, agg_ue, Wu_ue + 4096, bu_ue + 64, nullptr, nullptr,
        We_ua + 264, We_au + 264,
        Wp1, bp1, Wp2, bp2,
        x_ueB, nullptr, RueA, RueB, out_ue);
    node_ap_kernel<false, true><<<N_AP, blk, 0, stream>>>(
        partialA, CA, x_apA, Wu_ap + 4096, bu_ap + 64, nullptr, nullptr,
        We_ua + 328, be_ua + 4, We_au + 328, be_au + 4,
        out_ap, nullptr, RapA, RapB);

    // ---- final edge update (layer 4), original order ----
    final_edge<<<NE / 256, blk, 0, stream>>>(
        src, dst, invS, invD, attS, attD,
        RueA, RueB, RapA, RapB,
        We_ua + 392, We_au + 392, out_eua, out_eau);
}

// Round 12
// 1106.084 us; speedup vs baseline: 3.7896x; 3.7896x over previous
//
#include <hip/hip_runtime.h>
#include <math.h>

#define N_UE 16384
#define N_AP 128
#define NE   2097152
#define NSB  512                    // sort blocks
#define EPSB (NE / NSB)             // 4096 edges per sort block
#define CHS  16                     // src-side edges per chunk/thread
#define CHD  16                     // dst-side edges per chunk/thread
#define NEP  (NE + CHS * N_UE)      // padded src-sorted capacity 2359296
#define NCHU (NEP / CHS)            // 147456 src chunks
#define NEPD (NE + CHD * N_AP)      // padded dst-sorted capacity 2099200
#define NCHD_AL 131328              // 513*256 dst chunks (covers NEPD/CHD)
#define SRC_BLKS (NCHU / 256)       // 576
#define DST_BLKS (NCHD_AL / 256)    // 513

#define RFL(x) __int_as_float(__builtin_amdgcn_readfirstlane(__float_as_int(x)))

// ---------------------------------------------------------------------------
// prefill: sentinel records + chunk maps
// recS = (e0,e1, dt, origE) ; recD = (e0,e1, src, origE)
// ---------------------------------------------------------------------------
__global__ __launch_bounds__(256) void prefill(
    int4* __restrict__ recS, int4* __restrict__ recD,
    int* __restrict__ cnS, int* __restrict__ cnD)
{
    int i = blockIdx.x * 256 + threadIdx.x;    // grid = NEP/256
    recS[i] = make_int4(0, 0, N_AP, -1);       // sentinel AP row (-1e30)
    if (i < NEPD) recD[i] = make_int4(0, 0, N_UE, -1);
    if (i < NCHU) cnS[i] = -1;
    if (i < NCHD_AL) cnD[i] = -1;
}

// ---------------------------------------------------------------------------
// init tables + sentinel rows
// ---------------------------------------------------------------------------
__global__ __launch_bounds__(256) void init_kernel(
    const float* __restrict__ x_ue, const float* __restrict__ Wm1_ua,
    const float* __restrict__ bm1_ua, const float* __restrict__ bm1_au,
    float* __restrict__ Qua, float* __restrict__ Pau)
{
    int i = blockIdx.x * 256 + threadIdx.x;
    int d = i & 31;
    Qua[i] = fmaf(x_ue[i >> 5], Wm1_ua[d], bm1_ua[d]);
    if (i < N_AP * 32) Pau[i] = bm1_au[d];
    if (i < 32) { Qua[N_UE * 32 + i] = -1e30f; Pau[N_AP * 32 + i] = -1e30f; }
}

// ---------------------------------------------------------------------------
// fused histograms: src (u16-packed, 32KB LDS) + dst (512B LDS)
// ---------------------------------------------------------------------------
__global__ __launch_bounds__(256) void hist_both(
    const int* __restrict__ src, const int* __restrict__ dst,
    unsigned short* __restrict__ histS, int* __restrict__ histD)
{
    __shared__ unsigned int h32[N_UE / 2];   // 2 x u16 per word, 32KB
    __shared__ int hd[N_AP];
    const int tid = threadIdx.x, b = blockIdx.x;
    for (int i = tid; i < N_UE / 2; i += 256) h32[i] = 0u;
    if (tid < N_AP) hd[tid] = 0;
    __syncthreads();
    const int beg = b * EPSB;
    for (int e = beg + tid; e < beg + EPSB; e += 256) {
        int s = src[e];
        atomicAdd(&h32[s >> 1], 1u << ((s & 1) * 16));
        atomicAdd(&hd[dst[e]], 1);
    }
    __syncthreads();
    for (int i = tid; i < N_UE; i += 256)
        histS[(size_t)b * N_UE + i] =
            (unsigned short)((h32[i >> 1] >> ((i & 1) * 16)) & 0xffffu);
    if (tid < N_AP) histD[b * N_AP + tid] = hd[tid];
}

__global__ __launch_bounds__(256) void colscan_kernel(
    const unsigned short* __restrict__ histS,
    unsigned short* __restrict__ baseS, int* __restrict__ cnt)
{
    const int u = blockIdx.x * 256 + threadIdx.x;   // grid = N_UE/256
    int run = 0;
    for (int b = 0; b < NSB; ++b) {
        int t = histS[(size_t)b * N_UE + u];
        baseS[(size_t)b * N_UE + u] = (unsigned short)run;
        run += t;
    }
    cnt[u] = run;
}

__global__ __launch_bounds__(256) void scan_src(
    const int* __restrict__ cnt, int* __restrict__ CU)
{
    __shared__ int ps[256];
    __shared__ int ps2[257];
    const int t = threadIdx.x;
    const int b0 = t * (N_UE / 256);
    int s = 0;
    for (int i = 0; i < N_UE / 256; ++i) s += (cnt[b0 + i] + CHS - 1) / CHS;
    ps[t] = s;
    __syncthreads();
    if (t == 0) {
        int r = 0;
        for (int i = 0; i < 256; ++i) { ps2[i] = r; r += ps[i]; }
        ps2[256] = r;
    }
    __syncthreads();
    int r = ps2[t];
    for (int i = 0; i < N_UE / 256; ++i) { CU[b0 + i] = r; r += (cnt[b0 + i] + CHS - 1) / CHS; }
    if (t == 255) CU[N_UE] = ps2[256];
}

__global__ __launch_bounds__(128) void scan_dst(
    const int* __restrict__ histD, int* __restrict__ offsD, int* __restrict__ CA)
{
    __shared__ int colTot[N_AP], colStart[N_AP];
    const int a = threadIdx.x;
    int run = 0;
    for (int b = 0; b < NSB; ++b) {
        offsD[b * N_AP + a] = run;
        run += histD[b * N_AP + a];
    }
    colTot[a] = run;
    __syncthreads();
    if (a == 0) {
        int r = 0;
        for (int i = 0; i < N_AP; ++i) {
            CA[i] = r;
            colStart[i] = r * CHD;
            r += (colTot[i] + CHD - 1) / CHD;
        }
        CA[N_AP] = r;
    }
    __syncthreads();
    const int st = colStart[a];
    for (int b = 0; b < NSB; ++b) offsD[b * N_AP + a] += st;
}

// ---------------------------------------------------------------------------
// one-pass scatter: u16-packed LDS src cursor (32KB) + int dst cursor (512B).
// pos = CU[s]*CHS + baseS[b][s] + local (deterministic per block).
// One 16B record store per side; no inv arrays.
// ---------------------------------------------------------------------------
__global__ __launch_bounds__(256) void scatter_both(
    const int* __restrict__ src, const int* __restrict__ dst,
    const float2* __restrict__ e0ua, const float2* __restrict__ e0au,
    const unsigned short* __restrict__ baseS, const int* __restrict__ CU,
    const int* __restrict__ offsD,
    int4* __restrict__ recS, int4* __restrict__ recD)
{
    __shared__ unsigned int curS[N_UE / 2];   // 32KB packed u16 cursors
    __shared__ int curD[N_AP];
    const int tid = threadIdx.x, b = blockIdx.x;
    for (int i = tid; i < N_UE / 2; i += 256) curS[i] = 0u;
    if (tid < N_AP) curD[tid] = offsD[b * N_AP + tid];
    __syncthreads();
    const int beg = b * EPSB;
    for (int e = beg + tid; e < beg + EPSB; e += 256) {
        const int s = src[e], dt = dst[e];
        unsigned int old = atomicAdd(&curS[s >> 1], 1u << ((s & 1) * 16));
        int local = (int)((old >> ((s & 1) * 16)) & 0xffffu);
        int pos = CU[s] * CHS + (int)baseS[(size_t)b * N_UE + s] + local;
        float2 au = e0au[e];
        recS[pos] = make_int4(__float_as_int(au.x), __float_as_int(au.y), dt, e);
        int posd = atomicAdd(&curD[dt], 1);
        float2 ua = e0ua[e];
        recD[posd] = make_int4(__float_as_int(ua.x), __float_as_int(ua.y), s, e);
    }
}

// ---------------------------------------------------------------------------
// chunk maps
// ---------------------------------------------------------------------------
__global__ __launch_bounds__(256) void build_map_src(
    const int* __restrict__ CU, int* __restrict__ cnS)
{
    const int u = blockIdx.x * 256 + threadIdx.x;   // grid 64
    const int c0 = CU[u], c1 = CU[u + 1];
    for (int c = c0; c < c1; ++c) cnS[c] = u;
}

__global__ __launch_bounds__(128) void build_map_dst(
    const int* __restrict__ CA, int* __restrict__ cnD)
{
    const int a = threadIdx.x;
    const int c0 = CA[a], c1 = CA[a + 1];
    for (int c = c0; c < c1; ++c) cnD[c] = a;
}

// ---------------------------------------------------------------------------
// fused edge pass: blocks [0,SRC_BLKS) = src chunks; rest = dst chunks.
// thread = 16-edge chunk of ONE node -> partial row (no atomics, no LDS).
// ---------------------------------------------------------------------------
template<bool EUPD>
__global__ __launch_bounds__(256) void pass_both(
    const int* __restrict__ cnS, int4* __restrict__ recS,
    const int* __restrict__ cnD, int4* __restrict__ recD,
    const float2* __restrict__ RueA, const float2* __restrict__ RueB,
    const float2* __restrict__ RapA, const float2* __restrict__ RapB,
    const float* __restrict__ EcA, const float* __restrict__ EcB,
    const float* __restrict__ Qua, const float* __restrict__ Pau,
    const float* __restrict__ cu, const float* __restrict__ cw,
    float* __restrict__ partialU, float* __restrict__ partialA)
{
    if (blockIdx.x < SRC_BLKS) {
        const int ch = blockIdx.x * 256 + threadIdx.x;
        const int u = cnS[ch];
        if (u < 0) return;
        float w0v[32], w1v[32];
        #pragma unroll
        for (int d = 0; d < 32; ++d) { w0v[d] = RFL(cw[d]); w1v[d] = RFL(cw[32 + d]); }
        float d00 = 0.f, d01 = 0.f, d10 = 0.f, d11 = 0.f, rbx = 0.f, rby = 0.f;
        if constexpr (EUPD) {
            d00 = RFL(EcB[0]); d01 = RFL(EcB[1]); d10 = RFL(EcB[2]); d11 = RFL(EcB[3]);
            float2 r = RueB[u]; rbx = r.x; rby = r.y;
        }
        const float4* __restrict__ Pau4 = (const float4*)Pau;
        const int base = ch * CHS;
        float4 acc[8];
        #pragma unroll
        for (int q = 0; q < 8; ++q) acc[q] = make_float4(0.f, 0.f, 0.f, 0.f);
        #pragma unroll 4
        for (int j = 0; j < CHS; ++j) {
            int4 r4 = recS[base + j];
            int dt = r4.z;
            float2 a = make_float2(__int_as_float(r4.x), __int_as_float(r4.y));
            if constexpr (EUPD) {
                float2 rp = RapB[dt];
                float m0 = fmaxf(rbx + rp.x + a.x * d00 + a.y * d10, 0.f);
                float m1 = fmaxf(rby + rp.y + a.x * d01 + a.y * d11, 0.f);
                a = make_float2(m0, m1);
                *(float2*)&recS[base + j] = a;   // 8B aligned store at offset 0
            }
            const float4* pr = Pau4 + dt * 8;
            #pragma unroll
            for (int q = 0; q < 8; ++q) {
                float4 pv = pr[q];
                acc[q].x += fmaxf(fmaf(a.x, w0v[q*4+0], fmaf(a.y, w1v[q*4+0], pv.x)), 0.f);
                acc[q].y += fmaxf(fmaf(a.x, w0v[q*4+1], fmaf(a.y, w1v[q*4+1], pv.y)), 0.f);
                acc[q].z += fmaxf(fmaf(a.x, w0v[q*4+2], fmaf(a.y, w1v[q*4+2], pv.z)), 0.f);
                acc[q].w += fmaxf(fmaf(a.x, w0v[q*4+3], fmaf(a.y, w1v[q*4+3], pv.w)), 0.f);
            }
        }
        float4* pu = (float4*)(partialU + (size_t)ch * 32);
        #pragma unroll
        for (int q = 0; q < 8; ++q) pu[q] = acc[q];
    } else {
        const int ch = (blockIdx.x - SRC_BLKS) * 256 + threadIdx.x;
        const int a = cnD[ch];
        if (a < 0) return;
        float u0v[32], u1v[32];
        #pragma unroll
        for (int d = 0; d < 32; ++d) { u0v[d] = RFL(cu[d]); u1v[d] = RFL(cu[32 + d]); }
        float c00 = 0.f, c01 = 0.f, c10 = 0.f, c11 = 0.f, rax = 0.f, ray = 0.f;
        if constexpr (EUPD) {
            c00 = RFL(EcA[0]); c01 = RFL(EcA[1]); c10 = RFL(EcA[2]); c11 = RFL(EcA[3]);
            float2 r = RapA[a]; rax = r.x; ray = r.y;
        }
        const float4* __restrict__ Qua4 = (const float4*)Qua;
        const int base = ch * CHD;
        float4 acc[8];
        #pragma unroll
        for (int q = 0; q < 8; ++q) acc[q] = make_float4(0.f, 0.f, 0.f, 0.f);
        #pragma unroll 4
        for (int j = 0; j < CHD; ++j) {
            int4 r4 = recD[base + j];
            int s = r4.z;
            float2 a2 = make_float2(__int_as_float(r4.x), __int_as_float(r4.y));
            if constexpr (EUPD) {
                float2 ru = RueA[s];
                float n0 = fmaxf(rax + ru.x + a2.x * c00 + a2.y * c10, 0.f);
                float n1 = fmaxf(ray + ru.y + a2.x * c01 + a2.y * c11, 0.f);
                a2 = make_float2(n0, n1);
                *(float2*)&recD[base + j] = a2;
            }
            const float4* qr = Qua4 + s * 8;
            #pragma unroll
            for (int q = 0; q < 8; ++q) {
                float4 qv = qr[q];
                acc[q].x += fmaxf(fmaf(a2.x, u0v[q*4+0], fmaf(a2.y, u1v[q*4+0], qv.x)), 0.f);
                acc[q].y += fmaxf(fmaf(a2.x, u0v[q*4+1], fmaf(a2.y, u1v[q*4+1], qv.y)), 0.f);
                acc[q].z += fmaxf(fmaf(a2.x, u0v[q*4+2], fmaf(a2.y, u1v[q*4+2], qv.z)), 0.f);
                acc[q].w += fmaxf(fmaf(a2.x, u0v[q*4+3], fmaf(a2.y, u1v[q*4+3], qv.w)), 0.f);
            }
        }
        float4* pa = (float4*)(partialA + (size_t)ch * 32);
        #pragma unroll
        for (int q = 0; q < 8; ++q) pa[q] = acc[q];
    }
}

// ---------------------------------------------------------------------------
// reduce_ue: 32-lane group per node sums its chunk partial rows.
// ---------------------------------------------------------------------------
__global__ __launch_bounds__(256) void reduce_ue(
    const int* __restrict__ CU, const float* __restrict__ partialU,
    float* __restrict__ agg_ue)
{
    const int g   = (blockIdx.x * 256 + threadIdx.x) >> 5;   // node, grid=2048
    const int dim = threadIdx.x & 31;
    const int c0 = CU[g], c1 = CU[g + 1];
    float acc = 0.f;
    for (int c = c0; c < c1; ++c) acc += partialU[(size_t)c * 32 + dim];
    agg_ue[g * 32 + dim] = acc;
}

// ---------------------------------------------------------------------------
// Final layer-4 edge update: stream sorted records, node from chunk map,
// scatter-write to original order via record's origE.
// ---------------------------------------------------------------------------
__global__ __launch_bounds__(256) void final_edge(
    const int4* __restrict__ recS, const int4* __restrict__ recD,
    const int* __restrict__ cnS, const int* __restrict__ cnD,
    const float2* __restrict__ RueA, const float2* __restrict__ RueB,
    const float2* __restrict__ RapA, const float2* __restrict__ RapB,
    const float* __restrict__ EcA, const float* __restrict__ EcB,
    float2* __restrict__ out_eua, float2* __restrict__ out_eau)
{
    const int i = blockIdx.x * 256 + threadIdx.x;   // grid = NEP/256
    float c00 = EcA[0], c01 = EcA[1], c10 = EcA[2], c11 = EcA[3];
    float d00 = EcB[0], d01 = EcB[1], d10 = EcB[2], d11 = EcB[3];
    {
        int4 r = recS[i];
        if (r.z != N_AP) {
            const int u = cnS[i >> 4];              // CHS=16
            float2 a = make_float2(__int_as_float(r.x), __int_as_float(r.y));
            float2 rB = RueB[u], pB = RapB[r.z];
            float m0 = fmaxf(rB.x + pB.x + a.x * d00 + a.y * d10, 0.f);
            float m1 = fmaxf(rB.y + pB.y + a.x * d01 + a.y * d11, 0.f);
            out_eau[r.w] = make_float2(m0, m1);
        }
    }
    if (i < NEPD) {
        int4 r = recD[i];
        if (r.z != N_UE) {
            const int ap = cnD[i >> 4];             // CHD=16
            float2 a = make_float2(__int_as_float(r.x), __int_as_float(r.y));
            float2 rA = RueA[r.z], pA = RapA[ap];
            float n0 = fmaxf(rA.x + pA.x + a.x * c00 + a.y * c10, 0.f);
            float n1 = fmaxf(rA.y + pA.y + a.x * c01 + a.y * c11, 0.f);
            out_eua[r.w] = make_float2(n0, n1);
        }
    }
}

// ---------------------------------------------------------------------------
// UE node update + next-layer tables (+ power head for LAST). 64-thr blocks.
// ---------------------------------------------------------------------------
template<bool FIRST, bool LAST>
__global__ __launch_bounds__(64) void node_ue_kernel(
    const float* __restrict__ x_prev, const float* __restrict__ agg_ue,
    const float* __restrict__ Wu, const float* __restrict__ bu,
    const float* __restrict__ Wm_next, const float* __restrict__ bm_next,
    const float* __restrict__ WeUa, const float* __restrict__ WeUb,
    const float* __restrict__ Wp1, const float* __restrict__ bp1,
    const float* __restrict__ Wp2, const float* __restrict__ bp2,
    float* __restrict__ x_new, float* __restrict__ Qua_next,
    float2* __restrict__ RueA, float2* __restrict__ RueB,
    float2* __restrict__ ue_out)
{
    constexpr int KIN = FIRST ? 33 : 64;
    __shared__ float Wu_s[64 * 32];
    __shared__ float Wm_s[32 * 32];
    __shared__ float WeA_s[64], WeB_s[64];
    __shared__ float bu_s[32], bm_s[32];
    __shared__ float Wp1_s[32 * 16], bp1_s[16], Wp2_s[16];

    const int tid = threadIdx.x;
    for (int i = tid; i < KIN * 32; i += 64) Wu_s[i] = Wu[i];
    if (tid < 32) bu_s[tid] = bu[tid];
    if (!LAST) {
        for (int i = tid; i < 1024; i += 64) Wm_s[i] = Wm_next[i];
        if (tid < 32) bm_s[tid] = bm_next[tid];
    }
    { WeA_s[tid] = WeUa[tid]; WeB_s[tid] = WeUb[tid]; }
    if (LAST) {
        for (int i = tid; i < 512; i += 64) Wp1_s[i] = Wp1[i];
        if (tid < 16) { bp1_s[tid] = bp1[tid]; Wp2_s[tid] = Wp2[tid]; }
    }
    __syncthreads();

    const int u = blockIdx.x * 64 + tid;
    float in[KIN];
    if (FIRST) {
        in[0] = x_prev[u];
        #pragma unroll
        for (int k = 0; k < 32; ++k) in[1 + k] = agg_ue[u * 32 + k];
    } else {
        #pragma unroll
        for (int k = 0; k < 32; ++k) in[k] = x_prev[u * 32 + k];
        #pragma unroll
        for (int k = 0; k < 32; ++k) in[32 + k] = agg_ue[u * 32 + k];
    }
    float out[32];
    #pragma unroll
    for (int d = 0; d < 32; ++d) {
        float acc = bu_s[d];
        #pragma unroll
        for (int k = 0; k < KIN; ++k) acc = fmaf(in[k], Wu_s[k * 32 + d], acc);
        out[d] = fmaxf(acc, 0.f);
    }
    #pragma unroll
    for (int d = 0; d < 32; ++d) x_new[u * 32 + d] = out[d];
    if (!LAST) {
        #pragma unroll
        for (int d = 0; d < 32; ++d) {
            float acc = bm_s[d];
            #pragma unroll
            for (int k = 0; k < 32; ++k) acc = fmaf(out[k], Wm_s[k * 32 + d], acc);
            Qua_next[u * 32 + d] = acc;
        }
    }
    float r0 = 0.f, r1 = 0.f, s0 = 0.f, s1 = 0.f;
    #pragma unroll
    for (int k = 0; k < 32; ++k) {
        r0 = fmaf(out[k], WeA_s[k * 2],     r0);
        r1 = fmaf(out[k], WeA_s[k * 2 + 1], r1);
        s0 = fmaf(out[k], WeB_s[k * 2],     s0);
        s1 = fmaf(out[k], WeB_s[k * 2 + 1], s1);
    }
    RueA[u] = make_float2(r0, r1);
    RueB[u] = make_float2(s0, s1);
    if (LAST) {
        float z = bp2[0];
        #pragma unroll
        for (int j = 0; j < 16; ++j) {
            float h = bp1_s[j];
            #pragma unroll
            for (int k = 0; k < 32; ++k) h = fmaf(out[k], Wp1_s[k * 16 + j], h);
            z = fmaf(fmaxf(h, 0.f), Wp2_s[j], z);
        }
        float pw = 1.f / (1.f + expf(-z));
        ue_out[u] = make_float2(out[0], pw);
    }
}

// ---------------------------------------------------------------------------
// AP: reduce chunk partials (CA ranges) -> agg_ap, node update, tables
// ---------------------------------------------------------------------------
template<bool FIRST, bool LAST>
__global__ __launch_bounds__(256) void node_ap_kernel(
    const float* __restrict__ partialA, const int* __restrict__ CA,
    const float* __restrict__ x_prev,
    const float* __restrict__ Wu, const float* __restrict__ bu,
    const float* __restrict__ Wm_next, const float* __restrict__ bm_next,
    const float* __restrict__ WeA, const float* __restrict__ beA,
    const float* __restrict__ WeB, const float* __restrict__ beB,
    float* __restrict__ x_new, float* __restrict__ Pau_next,
    float2* __restrict__ RapA, float2* __restrict__ RapB)
{
    __shared__ float red[256];
    __shared__ float agg_s[32];
    __shared__ float xnew_s[32];
    const int a = blockIdx.x, tid = threadIdx.x;
    const int d = tid & 31, p0 = tid >> 5;
    const int c0 = CA[a], c1 = CA[a + 1];
    float acc = 0.f;
    for (int p = c0 + p0; p < c1; p += 8)
        acc += partialA[(size_t)p * 32 + d];
    red[tid] = acc;
    __syncthreads();
    if (tid < 32) {
        float s = 0.f;
        #pragma unroll
        for (int i = 0; i < 8; ++i) s += red[i * 32 + tid];
        agg_s[tid] = s;
    }
    __syncthreads();
    if (tid < 32) {
        float acc2 = bu[d];
        if (FIRST) {
            #pragma unroll
            for (int k = 0; k < 32; ++k) acc2 = fmaf(agg_s[k], Wu[k * 32 + d], acc2);
        } else {
            #pragma unroll
            for (int k = 0; k < 32; ++k) acc2 = fmaf(x_prev[a * 32 + k], Wu[k * 32 + d], acc2);
            #pragma unroll
            for (int k = 0; k < 32; ++k) acc2 = fmaf(agg_s[k], Wu[(32 + k) * 32 + d], acc2);
        }
        float xn = fmaxf(acc2, 0.f);
        xnew_s[d] = xn;
        x_new[a * 32 + d] = xn;
    }
    __syncthreads();
    if (!LAST) {
        if (tid < 32) {
            float acc3 = bm_next[d];
            #pragma unroll
            for (int k = 0; k < 32; ++k) acc3 = fmaf(xnew_s[k], Wm_next[k * 32 + d], acc3);
            Pau_next[a * 32 + d] = acc3;
        }
    }
    if (tid == 0) {
        float q0 = beA[0], q1 = beA[1], t0 = beB[0], t1 = beB[1];
        #pragma unroll
        for (int k = 0; k < 32; ++k) {
            q0 = fmaf(xnew_s[k], WeA[k * 2],     q0);
            q1 = fmaf(xnew_s[k], WeA[k * 2 + 1], q1);
            t0 = fmaf(xnew_s[k], WeB[k * 2],     t0);
            t1 = fmaf(xnew_s[k], WeB[k * 2 + 1], t1);
        }
        RapA[a] = make_float2(q0, q1);
        RapB[a] = make_float2(t0, t1);
    }
}

// ---------------------------------------------------------------------------
extern "C" void kernel_launch(void* const* d_in, const int* in_sizes, int n_in,
                              void* d_out_v, int out_size, void* d_ws, size_t ws_size,
                              hipStream_t stream)
{
    const float*  x_ue   = (const float*)d_in[0];
    const float2* e0ua   = (const float2*)d_in[1];
    const float2* e0au   = (const float2*)d_in[2];
    const int*    src    = (const int*)d_in[3];
    const int*    dst    = (const int*)d_in[4];
    const float* Wm1_ua = (const float*)d_in[5];
    const float* bm1_ua = (const float*)d_in[6];
    const float* Wm1_au = (const float*)d_in[7];
    const float* bm1_au = (const float*)d_in[8];
    const float* Wu1_ap = (const float*)d_in[9];
    const float* bu1_ap = (const float*)d_in[10];
    const float* Wu1_ue = (const float*)d_in[11];
    const float* bu1_ue = (const float*)d_in[12];
    const float* We1_ua = (const float*)d_in[13];
    const float* be1_ua = (const float*)d_in[14];
    const float* We1_au = (const float*)d_in[15];
    const float* be1_au = (const float*)d_in[16];
    const float* Wm_ua  = (const float*)d_in[17];
    const float* bm_ua  = (const float*)d_in[18];
    const float* Wm_au  = (const float*)d_in[19];
    const float* bm_au  = (const float*)d_in[20];
    const float* Wu_ap  = (const float*)d_in[21];
    const float* bu_ap  = (const float*)d_in[22];
    const float* Wu_ue  = (const float*)d_in[23];
    const float* bu_ue  = (const float*)d_in[24];
    const float* We_ua  = (const float*)d_in[25];
    const float* be_ua  = (const float*)d_in[26];
    const float* We_au  = (const float*)d_in[27];
    const float* be_au  = (const float*)d_in[28];
    const float* Wp1    = (const float*)d_in[29];
    const float* bp1    = (const float*)d_in[30];
    const float* Wp2    = (const float*)d_in[31];
    const float* bp2    = (const float*)d_in[32];

    float*  outp    = (float*)d_out_v;
    float2* out_ue  = (float2*)outp;                              // [16384][2]
    float*  out_ap  = outp + N_UE * 2;                            // [128][32]
    float2* out_eua = (float2*)(outp + N_UE * 2 + N_AP * 32);     // [E][2]
    float2* out_eau = (float2*)(outp + N_UE * 2 + N_AP * 32 + (size_t)NE * 2);

    float* ws = (float*)d_ws;
    float* x_ueA  = ws;          ws += N_UE * 32;
    float* x_ueB  = ws;          ws += N_UE * 32;
    float* x_apA  = ws;          ws += N_AP * 32;
    float* x_apB  = ws;          ws += N_AP * 32;
    float* agg_ue = ws;          ws += N_UE * 32;
    float* Qua    = ws;          ws += (N_UE + 1) * 32;
    float* Pau    = ws;          ws += (N_AP + 1) * 32;
    float2* RueA  = (float2*)ws; ws += (N_UE + 2) * 2;
    float2* RueB  = (float2*)ws; ws += (N_UE + 2) * 2;
    float2* RapA  = (float2*)ws; ws += (N_AP + 2) * 2;
    float2* RapB  = (float2*)ws; ws += (N_AP + 2) * 2;
    int* cnt     = (int*)ws;     ws += N_UE;
    int* CU      = (int*)ws;     ws += N_UE + 4;
    int* histD   = (int*)ws;     ws += NSB * N_AP;
    int* offsD   = (int*)ws;     ws += NSB * N_AP;
    int* CA      = (int*)ws;     ws += N_AP + 4;
    int* cnS     = (int*)ws;     ws += NCHU;
    int* cnD     = (int*)ws;     ws += NCHD_AL;
    int4* recS   = (int4*)ws;    ws += (size_t)NEP * 4;           // 36 MB
    int4* recD   = (int4*)ws;    ws += (size_t)NEPD * 4;          // 34 MB
    float* partialU = ws;        ws += (size_t)NCHU * 32;         // 18.9 MB
    float* partialA = ws;        ws += (size_t)NCHD_AL * 32;      // 16.8 MB
    unsigned short* histS = (unsigned short*)partialU;            // 16 MB alias
    unsigned short* baseS = (unsigned short*)partialA;            // 16 MB alias

    dim3 blk(256);

    // ---- sort structure ----
    prefill<<<NEP / 256, blk, 0, stream>>>(recS, recD, cnS, cnD);
    hist_both<<<NSB, blk, 0, stream>>>(src, dst, histS, histD);
    colscan_kernel<<<N_UE / 256, blk, 0, stream>>>(histS, baseS, cnt);
    scan_src<<<1, blk, 0, stream>>>(cnt, CU);
    scan_dst<<<1, dim3(128), 0, stream>>>(histD, offsD, CA);
    scatter_both<<<NSB, blk, 0, stream>>>(src, dst, e0ua, e0au, baseS, CU, offsD,
                                          recS, recD);
    build_map_src<<<N_UE / 256, blk, 0, stream>>>(CU, cnS);
    build_map_dst<<<1, dim3(128), 0, stream>>>(CA, cnD);

    init_kernel<<<N_UE * 32 / 256, blk, 0, stream>>>(x_ue, Wm1_ua, bm1_ua, bm1_au, Qua, Pau);

    const int PB = SRC_BLKS + DST_BLKS;

    // ---- layer 1 ----
    pass_both<false><<<PB, blk, 0, stream>>>(
        cnS, recS, cnD, recD,
        nullptr, nullptr, nullptr, nullptr, nullptr, nullptr,
        Qua, Pau, Wm1_ua + 32, Wm1_au, partialU, partialA);
    reduce_ue<<<N_UE * 32 / 256, blk, 0, stream>>>(CU, partialU, agg_ue);
    node_ue_kernel<true, false><<<N_UE / 64, dim3(64), 0, stream>>>(
        x_ue, agg_ue, Wu1_ue, bu1_ue, Wm_ua, bm_ua, We1_ua, We1_au,
        nullptr, nullptr, nullptr, nullptr,
        x_ueA, Qua, RueA, RueB, nullptr);
    node_ap_kernel<true, false><<<N_AP, blk, 0, stream>>>(
        partialA, CA, nullptr, Wu1_ap, bu1_ap, Wm_au, bm_au,
        We1_ua + 64, be1_ua, We1_au + 64, be1_au,
        x_apA, Pau, RapA, RapB);

    // ---- layer 2 (edge-update 1 fused) ----
    pass_both<true><<<PB, blk, 0, stream>>>(
        cnS, recS, cnD, recD,
        RueA, RueB, RapA, RapB, We1_ua + 128, We1_au + 128,
        Qua, Pau, Wm_ua + 1024, Wm_au + 1024, partialU, partialA);
    reduce_ue<<<N_UE * 32 / 256, blk, 0, stream>>>(CU, partialU, agg_ue);
    node_ue_kernel<false, false><<<N_UE / 64, dim3(64), 0, stream>>>(
        x_ueA, agg_ue, Wu_ue, bu_ue, Wm_ua + 1088, bm_ua + 32, We_ua, We_au,
        nullptr, nullptr, nullptr, nullptr,
        x_ueB, Qua, RueA, RueB, nullptr);
    node_ap_kernel<false, false><<<N_AP, blk, 0, stream>>>(
        partialA, CA, x_apA, Wu_ap, bu_ap, Wm_au + 1088, bm_au + 32,
        We_ua + 64, be_ua, We_au + 64, be_au,
        x_apB, Pau, RapA, RapB);

    // ---- layer 3 (edge-update 2 fused) ----
    pass_both<true><<<PB, blk, 0, stream>>>(
        cnS, recS, cnD, recD,
        RueA, RueB, RapA, RapB, We_ua + 128, We_au + 128,
        Qua, Pau, Wm_ua + 2112, Wm_au + 2112, partialU, partialA);
    reduce_ue<<<N_UE * 32 / 256, blk, 0, stream>>>(CU, partialU, agg_ue);
    node_ue_kernel<false, false><<<N_UE / 64, dim3(64), 0, stream>>>(
        x_ueB, agg_ue, Wu_ue + 2048, bu_ue + 32, Wm_ua + 2176, bm_ua + 64,
        We_ua + 132, We_au + 132,
        nullptr, nullptr, nullptr, nullptr,
        x_ueA, Qua, RueA, RueB, nullptr);
    node_ap_kernel<false, false><<<N_AP, blk, 0, stream>>>(
        partialA, CA, x_apB, Wu_ap + 2048, bu_ap + 32, Wm_au + 2176, bm_au + 64,
        We_ua + 196, be_ua + 2, We_au + 196, be_au + 2,
        x_apA, Pau, RapA, RapB);

    // ---- layer 4 (edge-update 3 fused) ----
    pass_both<true><<<PB, blk, 0, stream>>>(
        cnS, recS, cnD, recD,
        RueA, RueB, RapA, RapB, We_ua + 260, We_au + 260,
        Qua, Pau, Wm_ua + 3200, Wm_au + 3200, partialU, partialA);
    reduce_ue<<<N_UE * 32 / 256, blk, 0, stream>>>(CU, partialU, agg_ue);
    node_ue_kernel<false, true><<<N_UE / 64, dim3(64), 0, stream>>>(
        x_ueA, agg_ue, Wu_ue + 4096, bu_ue + 64, nullptr, nullptr,
        We_ua + 264, We_au + 264,
        Wp1, bp1, Wp2, bp2,
        x_ueB, nullptr, RueA, RueB, out_ue);
    node_ap_kernel<false, true><<<N_AP, blk, 0, stream>>>(
        partialA, CA, x_apA, Wu_ap + 4096, bu_ap + 64, nullptr, nullptr,
        We_ua + 328, be_ua + 4, We_au + 328, be_au + 4,
        out_ap, nullptr, RapA, RapB);

    // ---- final edge update (layer 4), original order via record origE ----
    final_edge<<<NEP / 256, blk, 0, stream>>>(
        recS, recD, cnS, cnD, RueA, RueB, RapA, RapB,
        We_ua + 392, We_au + 392, out_eua, out_eau);
}

// Round 13
// 1016.462 us; speedup vs baseline: 4.1238x; 1.0882x over previous
//
#include <hip/hip_runtime.h>
#include <math.h>

#define N_UE 16384
#define N_AP 128
#define NE   2097152
#define NSB  512                    // sort blocks
#define EPSB (NE / NSB)             // 4096 edges per sort block
#define CHS  16                     // src-side edges per chunk/thread
#define CHD  16                     // dst-side edges per chunk/thread
#define NEP  (NE + CHS * N_UE)      // padded src-sorted capacity 2359296
#define NCHU (NEP / CHS)            // 147456 src chunks
#define NEPD (NE + CHD * N_AP)      // padded dst-sorted capacity 2099200
#define NCHD_AL 131328              // 513*256 dst chunks (covers NEPD/CHD)
#define SRC_BLKS (NCHU / 256)       // 576
#define DST_BLKS (NCHD_AL / 256)    // 513

#define RFL(x) __int_as_float(__builtin_amdgcn_readfirstlane(__float_as_int(x)))

// ---------------------------------------------------------------------------
// prefill: sentinels in padded index arrays + chunk-map tails
// ---------------------------------------------------------------------------
__global__ __launch_bounds__(256) void prefill(
    int* __restrict__ dtS, int* __restrict__ srcD,
    int* __restrict__ cnS, int* __restrict__ cnD)
{
    int i = blockIdx.x * 256 + threadIdx.x;    // grid = NEP/256
    dtS[i] = N_AP;                             // sentinel AP row (-1e30)
    if (i < NEPD) srcD[i] = N_UE;              // sentinel UE row (-1e30)
    if (i < NCHU) cnS[i] = -1;
    if (i < NCHD_AL) cnD[i] = -1;
}

// ---------------------------------------------------------------------------
// init tables + sentinel rows
// ---------------------------------------------------------------------------
__global__ __launch_bounds__(256) void init_kernel(
    const float* __restrict__ x_ue, const float* __restrict__ Wm1_ua,
    const float* __restrict__ bm1_ua, const float* __restrict__ bm1_au,
    float* __restrict__ Qua, float* __restrict__ Pau)
{
    int i = blockIdx.x * 256 + threadIdx.x;
    int d = i & 31;
    Qua[i] = fmaf(x_ue[i >> 5], Wm1_ua[d], bm1_ua[d]);
    if (i < N_AP * 32) Pau[i] = bm1_au[d];
    if (i < 32) { Qua[N_UE * 32 + i] = -1e30f; Pau[N_AP * 32 + i] = -1e30f; }
}

// ---------------------------------------------------------------------------
// fused histograms: src (u16-packed, 32KB LDS) + dst (512B LDS); 512 threads
// ---------------------------------------------------------------------------
__global__ __launch_bounds__(512) void hist_both(
    const int* __restrict__ src, const int* __restrict__ dst,
    unsigned short* __restrict__ histS, int* __restrict__ histD)
{
    __shared__ unsigned int h32[N_UE / 2];   // 2 x u16 per word, 32KB
    __shared__ int hd[N_AP];
    const int tid = threadIdx.x, b = blockIdx.x;
    for (int i = tid; i < N_UE / 2; i += 512) h32[i] = 0u;
    if (tid < N_AP) hd[tid] = 0;
    __syncthreads();
    const int beg = b * EPSB;
    for (int e = beg + tid; e < beg + EPSB; e += 512) {
        int s = src[e];
        atomicAdd(&h32[s >> 1], 1u << ((s & 1) * 16));
        atomicAdd(&hd[dst[e]], 1);
    }
    __syncthreads();
    for (int i = tid; i < N_UE; i += 512)
        histS[(size_t)b * N_UE + i] =
            (unsigned short)((h32[i >> 1] >> ((i & 1) * 16)) & 0xffffu);
    if (tid < N_AP) histD[b * N_AP + tid] = hd[tid];
}

__global__ __launch_bounds__(256) void colscan_kernel(
    const unsigned short* __restrict__ histS,
    unsigned short* __restrict__ baseS, int* __restrict__ cnt)
{
    const int u = blockIdx.x * 256 + threadIdx.x;   // grid = N_UE/256
    int run = 0;
    for (int b = 0; b < NSB; ++b) {
        int t = histS[(size_t)b * N_UE + u];
        baseS[(size_t)b * N_UE + u] = (unsigned short)run;
        run += t;
    }
    cnt[u] = run;
}

__global__ __launch_bounds__(256) void scan_src(
    const int* __restrict__ cnt, int* __restrict__ CU)
{
    __shared__ int ps[256];
    __shared__ int ps2[257];
    const int t = threadIdx.x;
    const int b0 = t * (N_UE / 256);
    int s = 0;
    for (int i = 0; i < N_UE / 256; ++i) s += (cnt[b0 + i] + CHS - 1) / CHS;
    ps[t] = s;
    __syncthreads();
    if (t == 0) {
        int r = 0;
        for (int i = 0; i < 256; ++i) { ps2[i] = r; r += ps[i]; }
        ps2[256] = r;
    }
    __syncthreads();
    int r = ps2[t];
    for (int i = 0; i < N_UE / 256; ++i) { CU[b0 + i] = r; r += (cnt[b0 + i] + CHS - 1) / CHS; }
    if (t == 255) CU[N_UE] = ps2[256];
}

__global__ __launch_bounds__(128) void scan_dst(
    const int* __restrict__ histD, int* __restrict__ offsD, int* __restrict__ CA)
{
    __shared__ int colTot[N_AP], colStart[N_AP];
    const int a = threadIdx.x;
    int run = 0;
    for (int b = 0; b < NSB; ++b) {
        offsD[b * N_AP + a] = run;
        run += histD[b * N_AP + a];
    }
    colTot[a] = run;
    __syncthreads();
    if (a == 0) {
        int r = 0;
        for (int i = 0; i < N_AP; ++i) {
            CA[i] = r;
            colStart[i] = r * CHD;
            r += (colTot[i] + CHD - 1) / CHD;
        }
        CA[N_AP] = r;
    }
    __syncthreads();
    const int st = colStart[a];
    for (int b = 0; b < NSB; ++b) offsD[b * N_AP + a] += st;
}

// ---------------------------------------------------------------------------
// one-pass scatter: u16-packed LDS src cursor (32KB) + int dst cursor.
// pos = CU[s]*CHS + baseS[b][s] + local (deterministic per block). 512 thr.
// ---------------------------------------------------------------------------
__global__ __launch_bounds__(512) void scatter_both(
    const int* __restrict__ src, const int* __restrict__ dst,
    const float2* __restrict__ e0ua, const float2* __restrict__ e0au,
    const unsigned short* __restrict__ baseS, const int* __restrict__ CU,
    const int* __restrict__ offsD,
    int* __restrict__ dtS, float2* __restrict__ attS, int* __restrict__ invS,
    int* __restrict__ srcD, float2* __restrict__ attD, int* __restrict__ invD)
{
    __shared__ unsigned int curS[N_UE / 2];   // 32KB packed u16 cursors
    __shared__ int curD[N_AP];
    const int tid = threadIdx.x, b = blockIdx.x;
    for (int i = tid; i < N_UE / 2; i += 512) curS[i] = 0u;
    if (tid < N_AP) curD[tid] = offsD[b * N_AP + tid];
    __syncthreads();
    const int beg = b * EPSB;
    for (int e = beg + tid; e < beg + EPSB; e += 512) {
        const int s = src[e], dt = dst[e];
        unsigned int old = atomicAdd(&curS[s >> 1], 1u << ((s & 1) * 16));
        int local = (int)((old >> ((s & 1) * 16)) & 0xffffu);
        int pos = CU[s] * CHS + (int)baseS[(size_t)b * N_UE + s] + local;
        dtS[pos] = dt;
        attS[pos] = e0au[e];
        invS[e] = pos;
        int posd = atomicAdd(&curD[dt], 1);
        srcD[posd] = s;
        attD[posd] = e0ua[e];
        invD[e] = posd;
    }
}

// ---------------------------------------------------------------------------
// chunk maps
// ---------------------------------------------------------------------------
__global__ __launch_bounds__(256) void build_map_src(
    const int* __restrict__ CU, int* __restrict__ cnS)
{
    const int u = blockIdx.x * 256 + threadIdx.x;   // grid 64
    const int c0 = CU[u], c1 = CU[u + 1];
    for (int c = c0; c < c1; ++c) cnS[c] = u;
}

__global__ __launch_bounds__(128) void build_map_dst(
    const int* __restrict__ CA, int* __restrict__ cnD)
{
    const int a = threadIdx.x;
    const int c0 = CA[a], c1 = CA[a + 1];
    for (int c = c0; c < c1; ++c) cnD[c] = a;
}

// ---------------------------------------------------------------------------
// fused edge pass: blocks [0,SRC_BLKS) = src chunks; rest = dst chunks.
// thread = 16-edge chunk of ONE node -> partial row (no atomics, no LDS).
// ---------------------------------------------------------------------------
template<bool EUPD>
__global__ __launch_bounds__(256) void pass_both(
    const int* __restrict__ cnS, const int* __restrict__ dtS,
    float2* __restrict__ attS,
    const int* __restrict__ cnD, const int* __restrict__ srcD,
    float2* __restrict__ attD,
    const float2* __restrict__ RueA, const float2* __restrict__ RueB,
    const float2* __restrict__ RapA, const float2* __restrict__ RapB,
    const float* __restrict__ EcA, const float* __restrict__ EcB,
    const float* __restrict__ Qua, const float* __restrict__ Pau,
    const float* __restrict__ cu, const float* __restrict__ cw,
    float* __restrict__ partialU, float* __restrict__ partialA)
{
    if (blockIdx.x < SRC_BLKS) {
        const int ch = blockIdx.x * 256 + threadIdx.x;
        const int u = cnS[ch];
        if (u < 0) return;
        float w0v[32], w1v[32];
        #pragma unroll
        for (int d = 0; d < 32; ++d) { w0v[d] = RFL(cw[d]); w1v[d] = RFL(cw[32 + d]); }
        float d00 = 0.f, d01 = 0.f, d10 = 0.f, d11 = 0.f, rbx = 0.f, rby = 0.f;
        if constexpr (EUPD) {
            d00 = RFL(EcB[0]); d01 = RFL(EcB[1]); d10 = RFL(EcB[2]); d11 = RFL(EcB[3]);
            float2 r = RueB[u]; rbx = r.x; rby = r.y;
        }
        const float4* __restrict__ Pau4 = (const float4*)Pau;
        const int base = ch * CHS;
        float4 acc[8];
        #pragma unroll
        for (int q = 0; q < 8; ++q) acc[q] = make_float4(0.f, 0.f, 0.f, 0.f);
        #pragma unroll 4
        for (int j = 0; j < CHS; ++j) {
            int dt = dtS[base + j];
            float2 a = attS[base + j];
            if constexpr (EUPD) {
                float2 rp = RapB[dt];
                float m0 = fmaxf(rbx + rp.x + a.x * d00 + a.y * d10, 0.f);
                float m1 = fmaxf(rby + rp.y + a.x * d01 + a.y * d11, 0.f);
                a = make_float2(m0, m1);
                attS[base + j] = a;
            }
            const float4* pr = Pau4 + dt * 8;
            #pragma unroll
            for (int q = 0; q < 8; ++q) {
                float4 pv = pr[q];
                acc[q].x += fmaxf(fmaf(a.x, w0v[q*4+0], fmaf(a.y, w1v[q*4+0], pv.x)), 0.f);
                acc[q].y += fmaxf(fmaf(a.x, w0v[q*4+1], fmaf(a.y, w1v[q*4+1], pv.y)), 0.f);
                acc[q].z += fmaxf(fmaf(a.x, w0v[q*4+2], fmaf(a.y, w1v[q*4+2], pv.z)), 0.f);
                acc[q].w += fmaxf(fmaf(a.x, w0v[q*4+3], fmaf(a.y, w1v[q*4+3], pv.w)), 0.f);
            }
        }
        float4* pu = (float4*)(partialU + (size_t)ch * 32);
        #pragma unroll
        for (int q = 0; q < 8; ++q) pu[q] = acc[q];
    } else {
        const int ch = (blockIdx.x - SRC_BLKS) * 256 + threadIdx.x;
        const int a = cnD[ch];
        if (a < 0) return;
        float u0v[32], u1v[32];
        #pragma unroll
        for (int d = 0; d < 32; ++d) { u0v[d] = RFL(cu[d]); u1v[d] = RFL(cu[32 + d]); }
        float c00 = 0.f, c01 = 0.f, c10 = 0.f, c11 = 0.f, rax = 0.f, ray = 0.f;
        if constexpr (EUPD) {
            c00 = RFL(EcA[0]); c01 = RFL(EcA[1]); c10 = RFL(EcA[2]); c11 = RFL(EcA[3]);
            float2 r = RapA[a]; rax = r.x; ray = r.y;
        }
        const float4* __restrict__ Qua4 = (const float4*)Qua;
        const int base = ch * CHD;
        float4 acc[8];
        #pragma unroll
        for (int q = 0; q < 8; ++q) acc[q] = make_float4(0.f, 0.f, 0.f, 0.f);
        #pragma unroll 4
        for (int j = 0; j < CHD; ++j) {
            int s = srcD[base + j];
            float2 a2 = attD[base + j];
            if constexpr (EUPD) {
                float2 ru = RueA[s];
                float n0 = fmaxf(rax + ru.x + a2.x * c00 + a2.y * c10, 0.f);
                float n1 = fmaxf(ray + ru.y + a2.x * c01 + a2.y * c11, 0.f);
                a2 = make_float2(n0, n1);
                attD[base + j] = a2;
            }
            const float4* qr = Qua4 + s * 8;
            #pragma unroll
            for (int q = 0; q < 8; ++q) {
                float4 qv = qr[q];
                acc[q].x += fmaxf(fmaf(a2.x, u0v[q*4+0], fmaf(a2.y, u1v[q*4+0], qv.x)), 0.f);
                acc[q].y += fmaxf(fmaf(a2.x, u0v[q*4+1], fmaf(a2.y, u1v[q*4+1], qv.y)), 0.f);
                acc[q].z += fmaxf(fmaf(a2.x, u0v[q*4+2], fmaf(a2.y, u1v[q*4+2], qv.z)), 0.f);
                acc[q].w += fmaxf(fmaf(a2.x, u0v[q*4+3], fmaf(a2.y, u1v[q*4+3], qv.w)), 0.f);
            }
        }
        float4* pa = (float4*)(partialA + (size_t)ch * 32);
        #pragma unroll
        for (int q = 0; q < 8; ++q) pa[q] = acc[q];
    }
}

// ---------------------------------------------------------------------------
// reduce_ue: 32-lane group per node sums its chunk partial rows.
// ---------------------------------------------------------------------------
__global__ __launch_bounds__(256) void reduce_ue(
    const int* __restrict__ CU, const float* __restrict__ partialU,
    float* __restrict__ agg_ue)
{
    const int g   = (blockIdx.x * 256 + threadIdx.x) >> 5;   // node, grid=2048
    const int dim = threadIdx.x & 31;
    const int c0 = CU[g], c1 = CU[g + 1];
    float acc = 0.f;
    for (int c = c0; c < c1; ++c) acc += partialU[(size_t)c * 32 + dim];
    agg_ue[g * 32 + dim] = acc;
}

// ---------------------------------------------------------------------------
// Final layer-4 edge update, original order (gather via invS/invD).
// ---------------------------------------------------------------------------
__global__ __launch_bounds__(256) void final_edge(
    const int* __restrict__ src, const int* __restrict__ dst,
    const int* __restrict__ invS, const int* __restrict__ invD,
    const float2* __restrict__ attS, const float2* __restrict__ attD,
    const float2* __restrict__ RueA, const float2* __restrict__ RueB,
    const float2* __restrict__ RapA, const float2* __restrict__ RapB,
    const float* __restrict__ EcA, const float* __restrict__ EcB,
    float2* __restrict__ out_eua, float2* __restrict__ out_eau)
{
    const int e = blockIdx.x * 256 + threadIdx.x;
    const int s = src[e], dt = dst[e];
    float c00 = EcA[0], c01 = EcA[1], c10 = EcA[2], c11 = EcA[3];
    float d00 = EcB[0], d01 = EcB[1], d10 = EcB[2], d11 = EcB[3];
    float2 eua = attD[invD[e]];
    float2 eau = attS[invS[e]];
    float2 rA = RueA[s], pA = RapA[dt];
    float n0 = fmaxf(rA.x + pA.x + eua.x * c00 + eua.y * c10, 0.f);
    float n1 = fmaxf(rA.y + pA.y + eua.x * c01 + eua.y * c11, 0.f);
    float2 rB = RueB[s], pB = RapB[dt];
    float m0 = fmaxf(rB.x + pB.x + eau.x * d00 + eau.y * d10, 0.f);
    float m1 = fmaxf(rB.y + pB.y + eau.x * d01 + eau.y * d11, 0.f);
    out_eua[e] = make_float2(n0, n1);
    out_eau[e] = make_float2(m0, m1);
}

// ---------------------------------------------------------------------------
// UE node update + next-layer tables (+ power head for LAST). 64-thr blocks.
// ---------------------------------------------------------------------------
template<bool FIRST, bool LAST>
__global__ __launch_bounds__(64) void node_ue_kernel(
    const float* __restrict__ x_prev, const float* __restrict__ agg_ue,
    const float* __restrict__ Wu, const float* __restrict__ bu,
    const float* __restrict__ Wm_next, const float* __restrict__ bm_next,
    const float* __restrict__ WeUa, const float* __restrict__ WeUb,
    const float* __restrict__ Wp1, const float* __restrict__ bp1,
    const float* __restrict__ Wp2, const float* __restrict__ bp2,
    float* __restrict__ x_new, float* __restrict__ Qua_next,
    float2* __restrict__ RueA, float2* __restrict__ RueB,
    float2* __restrict__ ue_out)
{
    constexpr int KIN = FIRST ? 33 : 64;
    __shared__ float Wu_s[64 * 32];
    __shared__ float Wm_s[32 * 32];
    __shared__ float WeA_s[64], WeB_s[64];
    __shared__ float bu_s[32], bm_s[32];
    __shared__ float Wp1_s[32 * 16], bp1_s[16], Wp2_s[16];

    const int tid = threadIdx.x;
    for (int i = tid; i < KIN * 32; i += 64) Wu_s[i] = Wu[i];
    if (tid < 32) bu_s[tid] = bu[tid];
    if (!LAST) {
        for (int i = tid; i < 1024; i += 64) Wm_s[i] = Wm_next[i];
        if (tid < 32) bm_s[tid] = bm_next[tid];
    }
    { WeA_s[tid] = WeUa[tid]; WeB_s[tid] = WeUb[tid]; }
    if (LAST) {
        for (int i = tid; i < 512; i += 64) Wp1_s[i] = Wp1[i];
        if (tid < 16) { bp1_s[tid] = bp1[tid]; Wp2_s[tid] = Wp2[tid]; }
    }
    __syncthreads();

    const int u = blockIdx.x * 64 + tid;
    float in[KIN];
    if (FIRST) {
        in[0] = x_prev[u];
        #pragma unroll
        for (int k = 0; k < 32; ++k) in[1 + k] = agg_ue[u * 32 + k];
    } else {
        #pragma unroll
        for (int k = 0; k < 32; ++k) in[k] = x_prev[u * 32 + k];
        #pragma unroll
        for (int k = 0; k < 32; ++k) in[32 + k] = agg_ue[u * 32 + k];
    }
    float out[32];
    #pragma unroll
    for (int d = 0; d < 32; ++d) {
        float acc = bu_s[d];
        #pragma unroll
        for (int k = 0; k < KIN; ++k) acc = fmaf(in[k], Wu_s[k * 32 + d], acc);
        out[d] = fmaxf(acc, 0.f);
    }
    #pragma unroll
    for (int d = 0; d < 32; ++d) x_new[u * 32 + d] = out[d];
    if (!LAST) {
        #pragma unroll
        for (int d = 0; d < 32; ++d) {
            float acc = bm_s[d];
            #pragma unroll
            for (int k = 0; k < 32; ++k) acc = fmaf(out[k], Wm_s[k * 32 + d], acc);
            Qua_next[u * 32 + d] = acc;
        }
    }
    float r0 = 0.f, r1 = 0.f, s0 = 0.f, s1 = 0.f;
    #pragma unroll
    for (int k = 0; k < 32; ++k) {
        r0 = fmaf(out[k], WeA_s[k * 2],     r0);
        r1 = fmaf(out[k], WeA_s[k * 2 + 1], r1);
        s0 = fmaf(out[k], WeB_s[k * 2],     s0);
        s1 = fmaf(out[k], WeB_s[k * 2 + 1], s1);
    }
    RueA[u] = make_float2(r0, r1);
    RueB[u] = make_float2(s0, s1);
    if (LAST) {
        float z = bp2[0];
        #pragma unroll
        for (int j = 0; j < 16; ++j) {
            float h = bp1_s[j];
            #pragma unroll
            for (int k = 0; k < 32; ++k) h = fmaf(out[k], Wp1_s[k * 16 + j], h);
            z = fmaf(fmaxf(h, 0.f), Wp2_s[j], z);
        }
        float pw = 1.f / (1.f + expf(-z));
        ue_out[u] = make_float2(out[0], pw);
    }
}

// ---------------------------------------------------------------------------
// AP: reduce chunk partials (CA ranges) -> agg_ap, node update, tables
// ---------------------------------------------------------------------------
template<bool FIRST, bool LAST>
__global__ __launch_bounds__(256) void node_ap_kernel(
    const float* __restrict__ partialA, const int* __restrict__ CA,
    const float* __restrict__ x_prev,
    const float* __restrict__ Wu, const float* __restrict__ bu,
    const float* __restrict__ Wm_next, const float* __restrict__ bm_next,
    const float* __restrict__ WeA, const float* __restrict__ beA,
    const float* __restrict__ WeB, const float* __restrict__ beB,
    float* __restrict__ x_new, float* __restrict__ Pau_next,
    float2* __restrict__ RapA, float2* __restrict__ RapB)
{
    __shared__ float red[256];
    __shared__ float agg_s[32];
    __shared__ float xnew_s[32];
    const int a = blockIdx.x, tid = threadIdx.x;
    const int d = tid & 31, p0 = tid >> 5;
    const int c0 = CA[a], c1 = CA[a + 1];
    float acc = 0.f;
    for (int p = c0 + p0; p < c1; p += 8)
        acc += partialA[(size_t)p * 32 + d];
    red[tid] = acc;
    __syncthreads();
    if (tid < 32) {
        float s = 0.f;
        #pragma unroll
        for (int i = 0; i < 8; ++i) s += red[i * 32 + tid];
        agg_s[tid] = s;
    }
    __syncthreads();
    if (tid < 32) {
        float acc2 = bu[d];
        if (FIRST) {
            #pragma unroll
            for (int k = 0; k < 32; ++k) acc2 = fmaf(agg_s[k], Wu[k * 32 + d], acc2);
        } else {
            #pragma unroll
            for (int k = 0; k < 32; ++k) acc2 = fmaf(x_prev[a * 32 + k], Wu[k * 32 + d], acc2);
            #pragma unroll
            for (int k = 0; k < 32; ++k) acc2 = fmaf(agg_s[k], Wu[(32 + k) * 32 + d], acc2);
        }
        float xn = fmaxf(acc2, 0.f);
        xnew_s[d] = xn;
        x_new[a * 32 + d] = xn;
    }
    __syncthreads();
    if (!LAST) {
        if (tid < 32) {
            float acc3 = bm_next[d];
            #pragma unroll
            for (int k = 0; k < 32; ++k) acc3 = fmaf(xnew_s[k], Wm_next[k * 32 + d], acc3);
            Pau_next[a * 32 + d] = acc3;
        }
    }
    if (tid == 0) {
        float q0 = beA[0], q1 = beA[1], t0 = beB[0], t1 = beB[1];
        #pragma unroll
        for (int k = 0; k < 32; ++k) {
            q0 = fmaf(xnew_s[k], WeA[k * 2],     q0);
            q1 = fmaf(xnew_s[k], WeA[k * 2 + 1], q1);
            t0 = fmaf(xnew_s[k], WeB[k * 2],     t0);
            t1 = fmaf(xnew_s[k], WeB[k * 2 + 1], t1);
        }
        RapA[a] = make_float2(q0, q1);
        RapB[a] = make_float2(t0, t1);
    }
}

// ---------------------------------------------------------------------------
extern "C" void kernel_launch(void* const* d_in, const int* in_sizes, int n_in,
                              void* d_out_v, int out_size, void* d_ws, size_t ws_size,
                              hipStream_t stream)
{
    const float*  x_ue   = (const float*)d_in[0];
    const float2* e0ua   = (const float2*)d_in[1];
    const float2* e0au   = (const float2*)d_in[2];
    const int*    src    = (const int*)d_in[3];
    const int*    dst    = (const int*)d_in[4];
    const float* Wm1_ua = (const float*)d_in[5];
    const float* bm1_ua = (const float*)d_in[6];
    const float* Wm1_au = (const float*)d_in[7];
    const float* bm1_au = (const float*)d_in[8];
    const float* Wu1_ap = (const float*)d_in[9];
    const float* bu1_ap = (const float*)d_in[10];
    const float* Wu1_ue = (const float*)d_in[11];
    const float* bu1_ue = (const float*)d_in[12];
    const float* We1_ua = (const float*)d_in[13];
    const float* be1_ua = (const float*)d_in[14];
    const float* We1_au = (const float*)d_in[15];
    const float* be1_au = (const float*)d_in[16];
    const float* Wm_ua  = (const float*)d_in[17];
    const float* bm_ua  = (const float*)d_in[18];
    const float* Wm_au  = (const float*)d_in[19];
    const float* bm_au  = (const float*)d_in[20];
    const float* Wu_ap  = (const float*)d_in[21];
    const float* bu_ap  = (const float*)d_in[22];
    const float* Wu_ue  = (const float*)d_in[23];
    const float* bu_ue  = (const float*)d_in[24];
    const float* We_ua  = (const float*)d_in[25];
    const float* be_ua  = (const float*)d_in[26];
    const float* We_au  = (const float*)d_in[27];
    const float* be_au  = (const float*)d_in[28];
    const float* Wp1    = (const float*)d_in[29];
    const float* bp1    = (const float*)d_in[30];
    const float* Wp2    = (const float*)d_in[31];
    const float* bp2    = (const float*)d_in[32];

    float*  outp    = (float*)d_out_v;
    float2* out_ue  = (float2*)outp;                              // [16384][2]
    float*  out_ap  = outp + N_UE * 2;                            // [128][32]
    float2* out_eua = (float2*)(outp + N_UE * 2 + N_AP * 32);     // [E][2]
    float2* out_eau = (float2*)(outp + N_UE * 2 + N_AP * 32 + (size_t)NE * 2);

    float* ws = (float*)d_ws;
    float* x_ueA  = ws;          ws += N_UE * 32;
    float* x_ueB  = ws;          ws += N_UE * 32;
    float* x_apA  = ws;          ws += N_AP * 32;
    float* x_apB  = ws;          ws += N_AP * 32;
    float* agg_ue = ws;          ws += N_UE * 32;
    float* Qua    = ws;          ws += (N_UE + 1) * 32;
    float* Pau    = ws;          ws += (N_AP + 1) * 32;
    float2* RueA  = (float2*)ws; ws += (N_UE + 2) * 2;
    float2* RueB  = (float2*)ws; ws += (N_UE + 2) * 2;
    float2* RapA  = (float2*)ws; ws += (N_AP + 2) * 2;
    float2* RapB  = (float2*)ws; ws += (N_AP + 2) * 2;
    int* cnt     = (int*)ws;     ws += N_UE;
    int* CU      = (int*)ws;     ws += N_UE + 4;
    int* histD   = (int*)ws;     ws += NSB * N_AP;
    int* offsD   = (int*)ws;     ws += NSB * N_AP;
    int* CA      = (int*)ws;     ws += N_AP + 4;
    int* cnS     = (int*)ws;     ws += NCHU;
    int* cnD     = (int*)ws;     ws += NCHD_AL;
    int* invS    = (int*)ws;     ws += NE;
    int* invD    = (int*)ws;     ws += NE;
    int* dtS     = (int*)ws;     ws += NEP;
    int* srcD    = (int*)ws;     ws += NEPD;
    float2* attS = (float2*)ws;  ws += (size_t)NEP * 2;           // 18.9 MB
    float2* attD = (float2*)ws;  ws += (size_t)NEPD * 2;          // 16.8 MB
    float* partialU = ws;        ws += (size_t)NCHU * 32;         // 18.9 MB
    float* partialA = ws;        ws += (size_t)NCHD_AL * 32;      // 16.8 MB
    unsigned short* histS = (unsigned short*)partialU;            // 16 MB alias
    unsigned short* baseS = (unsigned short*)partialA;            // 16 MB alias

    dim3 blk(256);

    // ---- sort structure ----
    prefill<<<NEP / 256, blk, 0, stream>>>(dtS, srcD, cnS, cnD);
    hist_both<<<NSB, dim3(512), 0, stream>>>(src, dst, histS, histD);
    colscan_kernel<<<N_UE / 256, blk, 0, stream>>>(histS, baseS, cnt);
    scan_src<<<1, blk, 0, stream>>>(cnt, CU);
    scan_dst<<<1, dim3(128), 0, stream>>>(histD, offsD, CA);
    scatter_both<<<NSB, dim3(512), 0, stream>>>(src, dst, e0ua, e0au, baseS, CU,
                                                offsD, dtS, attS, invS,
                                                srcD, attD, invD);
    build_map_src<<<N_UE / 256, blk, 0, stream>>>(CU, cnS);
    build_map_dst<<<1, dim3(128), 0, stream>>>(CA, cnD);

    init_kernel<<<N_UE * 32 / 256, blk, 0, stream>>>(x_ue, Wm1_ua, bm1_ua, bm1_au, Qua, Pau);

    const int PB = SRC_BLKS + DST_BLKS;

    // ---- layer 1 ----
    pass_both<false><<<PB, blk, 0, stream>>>(
        cnS, dtS, attS, cnD, srcD, attD,
        nullptr, nullptr, nullptr, nullptr, nullptr, nullptr,
        Qua, Pau, Wm1_ua + 32, Wm1_au, partialU, partialA);
    reduce_ue<<<N_UE * 32 / 256, blk, 0, stream>>>(CU, partialU, agg_ue);
    node_ue_kernel<true, false><<<N_UE / 64, dim3(64), 0, stream>>>(
        x_ue, agg_ue, Wu1_ue, bu1_ue, Wm_ua, bm_ua, We1_ua, We1_au,
        nullptr, nullptr, nullptr, nullptr,
        x_ueA, Qua, RueA, RueB, nullptr);
    node_ap_kernel<true, false><<<N_AP, blk, 0, stream>>>(
        partialA, CA, nullptr, Wu1_ap, bu1_ap, Wm_au, bm_au,
        We1_ua + 64, be1_ua, We1_au + 64, be1_au,
        x_apA, Pau, RapA, RapB);

    // ---- layer 2 (edge-update 1 fused) ----
    pass_both<true><<<PB, blk, 0, stream>>>(
        cnS, dtS, attS, cnD, srcD, attD,
        RueA, RueB, RapA, RapB, We1_ua + 128, We1_au + 128,
        Qua, Pau, Wm_ua + 1024, Wm_au + 1024, partialU, partialA);
    reduce_ue<<<N_UE * 32 / 256, blk, 0, stream>>>(CU, partialU, agg_ue);
    node_ue_kernel<false, false><<<N_UE / 64, dim3(64), 0, stream>>>(
        x_ueA, agg_ue, Wu_ue, bu_ue, Wm_ua + 1088, bm_ua + 32, We_ua, We_au,
        nullptr, nullptr, nullptr, nullptr,
        x_ueB, Qua, RueA, RueB, nullptr);
    node_ap_kernel<false, false><<<N_AP, blk, 0, stream>>>(
        partialA, CA, x_apA, Wu_ap, bu_ap, Wm_au + 1088, bm_au + 32,
        We_ua + 64, be_ua, We_au + 64, be_au,
        x_apB, Pau, RapA, RapB);

    // ---- layer 3 (edge-update 2 fused) ----
    pass_both<true><<<PB, blk, 0, stream>>>(
        cnS, dtS, attS, cnD, srcD, attD,
        RueA, RueB, RapA, RapB, We_ua + 128, We_au + 128,
        Qua, Pau, Wm_ua + 2112, Wm_au + 2112, partialU, partialA);
    reduce_ue<<<N_UE * 32 / 256, blk, 0, stream>>>(CU, partialU, agg_ue);
    node_ue_kernel<false, false><<<N_UE / 64, dim3(64), 0, stream>>>(
        x_ueB, agg_ue, Wu_ue + 2048, bu_ue + 32, Wm_ua + 2176, bm_ua + 64,
        We_ua + 132, We_au + 132,
        nullptr, nullptr, nullptr, nullptr,
        x_ueA, Qua, RueA, RueB, nullptr);
    node_ap_kernel<false, false><<<N_AP, blk, 0, stream>>>(
        partialA, CA, x_apB, Wu_ap + 2048, bu_ap + 32, Wm_au + 2176, bm_au + 64,
        We_ua + 196, be_ua + 2, We_au + 196, be_au + 2,
        x_apA, Pau, RapA, RapB);

    // ---- layer 4 (edge-update 3 fused) ----
    pass_both<true><<<PB, blk, 0, stream>>>(
        cnS, dtS, attS, cnD, srcD, attD,
        RueA, RueB, RapA, RapB, We_ua + 260, We_au + 260,
        Qua, Pau, Wm_ua + 3200, Wm_au + 3200, partialU, partialA);
    reduce_ue<<<N_UE * 32 / 256, blk, 0, stream>>>(CU, partialU, agg_ue);
    node_ue_kernel<false, true><<<N_UE / 64, dim3(64), 0, stream>>>(
        x_ueA, agg_ue, Wu_ue + 4096, bu_ue + 64, nullptr, nullptr,
        We_ua + 264, We_au + 264,
        Wp1, bp1, Wp2, bp2,
        x_ueB, nullptr, RueA, RueB, out_ue);
    node_ap_kernel<false, true><<<N_AP, blk, 0, stream>>>(
        partialA, CA, x_apA, Wu_ap + 4096, bu_ap + 64, nullptr, nullptr,
        We_ua + 328, be_ua + 4, We_au + 328, be_au + 4,
        out_ap, nullptr, RapA, RapB);

    // ---- final edge update (layer 4), original order ----
    final_edge<<<NE / 256, blk, 0, stream>>>(
        src, dst, invS, invD, attS, attD,
        RueA, RueB, RapA, RapB,
        We_ua + 392, We_au + 392, out_eua, out_eau);
}

// Round 14
// 919.908 us; speedup vs baseline: 4.5566x; 1.1050x over previous
//
#include <hip/hip_runtime.h>
#include <math.h>

#define N_UE 16384
#define N_AP 128
#define NE   2097152
#define NSB  256                    // sort blocks
#define EPSB (NE / NSB)             // 8192 edges per sort block
#define NHALF (N_UE / 2)            // scatter sub-pass node range
#define CHS  8                      // src-side edges per chunk/thread
#define CHD  16                     // dst-side edges per chunk/thread
#define NEP  (NE + CHS * N_UE)      // padded src-sorted capacity 2228224
#define NCHU (NEP / CHS)            // 278528 src chunks
#define NEPD (NE + CHD * N_AP)      // padded dst-sorted capacity 2099200
#define NCHD_AL 131328              // 513*256 dst chunks
#define SRC_BLKS (NCHU / 256)       // 1088
#define DST_BLKS (NCHD_AL / 256)    // 513

#define RFL(x) __int_as_float(__builtin_amdgcn_readfirstlane(__float_as_int(x)))

// ---------------------------------------------------------------------------
// init tables + sentinel rows
// ---------------------------------------------------------------------------
__global__ __launch_bounds__(256) void init_kernel(
    const float* __restrict__ x_ue, const float* __restrict__ Wm1_ua,
    const float* __restrict__ bm1_ua, const float* __restrict__ bm1_au,
    float* __restrict__ Qua, float* __restrict__ Pau)
{
    int i = blockIdx.x * 256 + threadIdx.x;
    int d = i & 31;
    Qua[i] = fmaf(x_ue[i >> 5], Wm1_ua[d], bm1_ua[d]);
    if (i < N_AP * 32) Pau[i] = bm1_au[d];
    if (i < 32) { Qua[N_UE * 32 + i] = -1e30f; Pau[N_AP * 32 + i] = -1e30f; }
}

// ---------------------------------------------------------------------------
// fused histograms: src (u16-packed, 32KB LDS) + dst (512B LDS)
// ---------------------------------------------------------------------------
__global__ __launch_bounds__(256) void hist_both(
    const int* __restrict__ src, const int* __restrict__ dst,
    unsigned short* __restrict__ histS, int* __restrict__ histD)
{
    __shared__ unsigned int h32[N_UE / 2];   // 2 x u16 per word, 32KB
    __shared__ int hd[N_AP];
    const int tid = threadIdx.x, b = blockIdx.x;
    for (int i = tid; i < N_UE / 2; i += 256) h32[i] = 0u;
    if (tid < N_AP) hd[tid] = 0;
    __syncthreads();
    const int beg = b * EPSB;
    for (int e = beg + tid; e < beg + EPSB; e += 256) {
        int s = src[e];
        atomicAdd(&h32[s >> 1], 1u << ((s & 1) * 16));
        atomicAdd(&hd[dst[e]], 1);
    }
    __syncthreads();
    for (int i = tid; i < N_UE; i += 256)
        histS[(size_t)b * N_UE + i] =
            (unsigned short)((h32[i >> 1] >> ((i & 1) * 16)) & 0xffffu);
    if (tid < N_AP) histD[b * N_AP + tid] = hd[tid];
}

__global__ __launch_bounds__(256) void colscan_kernel(
    const unsigned short* __restrict__ histS,
    unsigned short* __restrict__ baseS, int* __restrict__ cnt)
{
    const int u = blockIdx.x * 256 + threadIdx.x;
    int run = 0;
    for (int b = 0; b < NSB; ++b) {
        int t = histS[(size_t)b * N_UE + u];
        baseS[(size_t)b * N_UE + u] = (unsigned short)run;
        run += t;
    }
    cnt[u] = run;
}

__global__ __launch_bounds__(256) void scan_src(
    const int* __restrict__ cnt, int* __restrict__ CU)
{
    __shared__ int ps[256];
    __shared__ int ps2[257];
    const int t = threadIdx.x;
    const int b0 = t * (N_UE / 256);
    int s = 0;
    for (int i = 0; i < N_UE / 256; ++i) s += (cnt[b0 + i] + CHS - 1) / CHS;
    ps[t] = s;
    __syncthreads();
    if (t == 0) {
        int r = 0;
        for (int i = 0; i < 256; ++i) { ps2[i] = r; r += ps[i]; }
        ps2[256] = r;
    }
    __syncthreads();
    int r = ps2[t];
    for (int i = 0; i < N_UE / 256; ++i) { CU[b0 + i] = r; r += (cnt[b0 + i] + CHS - 1) / CHS; }
    if (t == 255) CU[N_UE] = ps2[256];
}

__global__ __launch_bounds__(128) void scan_dst(
    const int* __restrict__ histD, int* __restrict__ offsD,
    int* __restrict__ CA, int* __restrict__ cntD)
{
    __shared__ int colTot[N_AP], colStart[N_AP];
    const int a = threadIdx.x;
    int run = 0;
    for (int b = 0; b < NSB; ++b) {
        offsD[b * N_AP + a] = run;
        run += histD[b * N_AP + a];
    }
    colTot[a] = run;
    cntD[a] = run;
    __syncthreads();
    if (a == 0) {
        int r = 0;
        for (int i = 0; i < N_AP; ++i) {
            CA[i] = r;
            colStart[i] = r * CHD;
            r += (colTot[i] + CHD - 1) / CHD;
        }
        CA[N_AP] = r;
    }
    __syncthreads();
    const int st = colStart[a];
    for (int b = 0; b < NSB; ++b) offsD[b * N_AP + a] += st;
}

// ---------------------------------------------------------------------------
// fused scatter: 2 sub-passes over src node-halves (32KB cursor) + dst
// scatter folded into pass 0. src side: ONE int4 record store + inv store.
// recS = (e_au.x bits, e_au.y bits, dt, origE)
// ---------------------------------------------------------------------------
__global__ __launch_bounds__(256) void scatter_both(
    const int* __restrict__ src, const int* __restrict__ dst,
    const float2* __restrict__ e0ua, const float2* __restrict__ e0au,
    const unsigned short* __restrict__ baseS, const int* __restrict__ CU,
    const int* __restrict__ offsD,
    int4* __restrict__ recS, int* __restrict__ invS,
    int* __restrict__ srcD, float2* __restrict__ attD, int* __restrict__ invD)
{
    __shared__ int cursor[NHALF];    // 32KB
    __shared__ int cursord[N_AP];
    const int tid = threadIdx.x, b = blockIdx.x;
    const int beg = b * EPSB;
    if (tid < N_AP) cursord[tid] = offsD[b * N_AP + tid];
    for (int p = 0; p < 2; ++p) {
        const int lo = p * NHALF;
        for (int i = tid; i < NHALF; i += 256)
            cursor[i] = CU[lo + i] * CHS + (int)baseS[(size_t)b * N_UE + lo + i];
        __syncthreads();
        for (int e = beg + tid; e < beg + EPSB; e += 256) {
            int s = src[e];
            int dt = dst[e];
            if (p == 0) {
                int posd = atomicAdd(&cursord[dt], 1);
                srcD[posd] = s;
                attD[posd] = e0ua[e];
                invD[e] = posd;
            }
            if (s >= lo && s < lo + NHALF) {
                int pos = atomicAdd(&cursor[s - lo], 1);
                float2 au = e0au[e];
                recS[pos] = make_int4(__float_as_int(au.x), __float_as_int(au.y), dt, e);
                invS[e] = pos;
            }
        }
        __syncthreads();
    }
}

// ---------------------------------------------------------------------------
// chunk maps + sentinel pads (replaces prefill)
// ---------------------------------------------------------------------------
__global__ __launch_bounds__(256) void build_map_src(
    const int* __restrict__ CU, const int* __restrict__ cnt,
    int* __restrict__ cnS, int4* __restrict__ recS)
{
    const int u = blockIdx.x * 256 + threadIdx.x;   // grid 64
    const int c0 = CU[u], c1 = CU[u + 1];
    for (int c = c0; c < c1; ++c) cnS[c] = u;
    // pad slots of this node: sentinel dt
    int* recw = (int*)recS;
    for (int pos = c0 * CHS + cnt[u]; pos < c1 * CHS; ++pos)
        recw[pos * 4 + 2] = N_AP;
    // tail chunks beyond last used
    const int gid = blockIdx.x * 256 + threadIdx.x;
    const int cend = CU[N_UE];
    for (int c = cend + gid; c < NCHU; c += N_UE) cnS[c] = -1;
}

__global__ __launch_bounds__(128) void build_map_dst(
    const int* __restrict__ CA, const int* __restrict__ cntD,
    int* __restrict__ cnD, int* __restrict__ srcD)
{
    const int a = threadIdx.x;
    const int c0 = CA[a], c1 = CA[a + 1];
    for (int c = c0; c < c1; ++c) cnD[c] = a;
    for (int pos = c0 * CHD + cntD[a]; pos < c1 * CHD; ++pos)
        srcD[pos] = N_UE;
    const int cend = CA[N_AP];
    for (int c = cend + a; c < NCHD_AL; c += 128) cnD[c] = -1;
}

// ---------------------------------------------------------------------------
// fused edge pass: blocks [0,SRC_BLKS) = src chunks; rest = dst chunks.
// src: thread = 8-edge chunk of ONE UE node (recS int4) -> partialU row.
// dst: thread = 16-edge chunk of ONE AP node -> partialA row. No atomics.
// ---------------------------------------------------------------------------
template<bool EUPD>
__global__ __launch_bounds__(256) void pass_both(
    const int* __restrict__ cnS, int4* __restrict__ recS,
    const int* __restrict__ cnD, const int* __restrict__ srcD,
    float2* __restrict__ attD,
    const float2* __restrict__ RueA, const float2* __restrict__ RueB,
    const float2* __restrict__ RapA, const float2* __restrict__ RapB,
    const float* __restrict__ EcA, const float* __restrict__ EcB,
    const float* __restrict__ Qua, const float* __restrict__ Pau,
    const float* __restrict__ cu, const float* __restrict__ cw,
    float* __restrict__ partialU, float* __restrict__ partialA)
{
    if (blockIdx.x < SRC_BLKS) {
        const int ch = blockIdx.x * 256 + threadIdx.x;
        const int u = cnS[ch];
        if (u < 0) return;
        float w0v[32], w1v[32];
        #pragma unroll
        for (int d = 0; d < 32; ++d) { w0v[d] = RFL(cw[d]); w1v[d] = RFL(cw[32 + d]); }
        float d00 = 0.f, d01 = 0.f, d10 = 0.f, d11 = 0.f, rbx = 0.f, rby = 0.f;
        if constexpr (EUPD) {
            d00 = RFL(EcB[0]); d01 = RFL(EcB[1]); d10 = RFL(EcB[2]); d11 = RFL(EcB[3]);
            float2 r = RueB[u]; rbx = r.x; rby = r.y;
        }
        const float4* __restrict__ Pau4 = (const float4*)Pau;
        const int base = ch * CHS;
        float4 acc[8];
        #pragma unroll
        for (int q = 0; q < 8; ++q) acc[q] = make_float4(0.f, 0.f, 0.f, 0.f);
        #pragma unroll
        for (int j = 0; j < CHS; ++j) {
            int4 r4 = recS[base + j];
            int dt = r4.z;
            float2 a = make_float2(__int_as_float(r4.x), __int_as_float(r4.y));
            if constexpr (EUPD) {
                float2 rp = RapB[dt];
                float m0 = fmaxf(rbx + rp.x + a.x * d00 + a.y * d10, 0.f);
                float m1 = fmaxf(rby + rp.y + a.x * d01 + a.y * d11, 0.f);
                a = make_float2(m0, m1);
                *(float2*)&recS[base + j] = a;   // 8B store, keeps .z/.w
            }
            const float4* pr = Pau4 + dt * 8;
            #pragma unroll
            for (int q = 0; q < 8; ++q) {
                float4 pv = pr[q];
                acc[q].x += fmaxf(fmaf(a.x, w0v[q*4+0], fmaf(a.y, w1v[q*4+0], pv.x)), 0.f);
                acc[q].y += fmaxf(fmaf(a.x, w0v[q*4+1], fmaf(a.y, w1v[q*4+1], pv.y)), 0.f);
                acc[q].z += fmaxf(fmaf(a.x, w0v[q*4+2], fmaf(a.y, w1v[q*4+2], pv.z)), 0.f);
                acc[q].w += fmaxf(fmaf(a.x, w0v[q*4+3], fmaf(a.y, w1v[q*4+3], pv.w)), 0.f);
            }
        }
        float4* pu = (float4*)(partialU + (size_t)ch * 32);
        #pragma unroll
        for (int q = 0; q < 8; ++q) pu[q] = acc[q];
    } else {
        const int ch = (blockIdx.x - SRC_BLKS) * 256 + threadIdx.x;
        const int a = cnD[ch];
        if (a < 0) return;
        float u0v[32], u1v[32];
        #pragma unroll
        for (int d = 0; d < 32; ++d) { u0v[d] = RFL(cu[d]); u1v[d] = RFL(cu[32 + d]); }
        float c00 = 0.f, c01 = 0.f, c10 = 0.f, c11 = 0.f, rax = 0.f, ray = 0.f;
        if constexpr (EUPD) {
            c00 = RFL(EcA[0]); c01 = RFL(EcA[1]); c10 = RFL(EcA[2]); c11 = RFL(EcA[3]);
            float2 r = RapA[a]; rax = r.x; ray = r.y;
        }
        const float4* __restrict__ Qua4 = (const float4*)Qua;
        const int base = ch * CHD;
        float4 acc[8];
        #pragma unroll
        for (int q = 0; q < 8; ++q) acc[q] = make_float4(0.f, 0.f, 0.f, 0.f);
        #pragma unroll 4
        for (int j = 0; j < CHD; ++j) {
            int s = srcD[base + j];
            float2 a2 = attD[base + j];
            if constexpr (EUPD) {
                float2 ru = RueA[s];
                float n0 = fmaxf(rax + ru.x + a2.x * c00 + a2.y * c10, 0.f);
                float n1 = fmaxf(ray + ru.y + a2.x * c01 + a2.y * c11, 0.f);
                a2 = make_float2(n0, n1);
                attD[base + j] = a2;
            }
            const float4* qr = Qua4 + s * 8;
            #pragma unroll
            for (int q = 0; q < 8; ++q) {
                float4 qv = qr[q];
                acc[q].x += fmaxf(fmaf(a2.x, u0v[q*4+0], fmaf(a2.y, u1v[q*4+0], qv.x)), 0.f);
                acc[q].y += fmaxf(fmaf(a2.x, u0v[q*4+1], fmaf(a2.y, u1v[q*4+1], qv.y)), 0.f);
                acc[q].z += fmaxf(fmaf(a2.x, u0v[q*4+2], fmaf(a2.y, u1v[q*4+2], qv.z)), 0.f);
                acc[q].w += fmaxf(fmaf(a2.x, u0v[q*4+3], fmaf(a2.y, u1v[q*4+3], qv.w)), 0.f);
            }
        }
        float4* pa = (float4*)(partialA + (size_t)ch * 32);
        #pragma unroll
        for (int q = 0; q < 8; ++q) pa[q] = acc[q];
    }
}

// ---------------------------------------------------------------------------
// reduce_ue: 32-lane group per node sums its chunk partial rows.
// ---------------------------------------------------------------------------
__global__ __launch_bounds__(256) void reduce_ue(
    const int* __restrict__ CU, const float* __restrict__ partialU,
    float* __restrict__ agg_ue)
{
    const int g   = (blockIdx.x * 256 + threadIdx.x) >> 5;   // node, grid=2048
    const int dim = threadIdx.x & 31;
    const int c0 = CU[g], c1 = CU[g + 1];
    float acc = 0.f;
    for (int c = c0; c < c1; ++c) acc += partialU[(size_t)c * 32 + dim];
    agg_ue[g * 32 + dim] = acc;
}

// ---------------------------------------------------------------------------
// Final layer-4 edge update, original order (gather via invS/invD).
// ---------------------------------------------------------------------------
__global__ __launch_bounds__(256) void final_edge(
    const int* __restrict__ src, const int* __restrict__ dst,
    const int* __restrict__ invS, const int* __restrict__ invD,
    const int4* __restrict__ recS, const float2* __restrict__ attD,
    const float2* __restrict__ RueA, const float2* __restrict__ RueB,
    const float2* __restrict__ RapA, const float2* __restrict__ RapB,
    const float* __restrict__ EcA, const float* __restrict__ EcB,
    float2* __restrict__ out_eua, float2* __restrict__ out_eau)
{
    const int e = blockIdx.x * 256 + threadIdx.x;
    const int s = src[e], dt = dst[e];
    float c00 = EcA[0], c01 = EcA[1], c10 = EcA[2], c11 = EcA[3];
    float d00 = EcB[0], d01 = EcB[1], d10 = EcB[2], d11 = EcB[3];
    float2 eua = attD[invD[e]];
    float2 eau = *(const float2*)(recS + invS[e]);
    float2 rA = RueA[s], pA = RapA[dt];
    float n0 = fmaxf(rA.x + pA.x + eua.x * c00 + eua.y * c10, 0.f);
    float n1 = fmaxf(rA.y + pA.y + eua.x * c01 + eua.y * c11, 0.f);
    float2 rB = RueB[s], pB = RapB[dt];
    float m0 = fmaxf(rB.x + pB.x + eau.x * d00 + eau.y * d10, 0.f);
    float m1 = fmaxf(rB.y + pB.y + eau.x * d01 + eau.y * d11, 0.f);
    out_eua[e] = make_float2(n0, n1);
    out_eau[e] = make_float2(m0, m1);
}

// ---------------------------------------------------------------------------
// UE node update + next-layer tables (+ power head for LAST). 64-thr blocks.
// ---------------------------------------------------------------------------
template<bool FIRST, bool LAST>
__global__ __launch_bounds__(64) void node_ue_kernel(
    const float* __restrict__ x_prev, const float* __restrict__ agg_ue,
    const float* __restrict__ Wu, const float* __restrict__ bu,
    const float* __restrict__ Wm_next, const float* __restrict__ bm_next,
    const float* __restrict__ WeUa, const float* __restrict__ WeUb,
    const float* __restrict__ Wp1, const float* __restrict__ bp1,
    const float* __restrict__ Wp2, const float* __restrict__ bp2,
    float* __restrict__ x_new, float* __restrict__ Qua_next,
    float2* __restrict__ RueA, float2* __restrict__ RueB,
    float2* __restrict__ ue_out)
{
    constexpr int KIN = FIRST ? 33 : 64;
    __shared__ float Wu_s[64 * 32];
    __shared__ float Wm_s[32 * 32];
    __shared__ float WeA_s[64], WeB_s[64];
    __shared__ float bu_s[32], bm_s[32];
    __shared__ float Wp1_s[32 * 16], bp1_s[16], Wp2_s[16];

    const int tid = threadIdx.x;
    for (int i = tid; i < KIN * 32; i += 64) Wu_s[i] = Wu[i];
    if (tid < 32) bu_s[tid] = bu[tid];
    if (!LAST) {
        for (int i = tid; i < 1024; i += 64) Wm_s[i] = Wm_next[i];
        if (tid < 32) bm_s[tid] = bm_next[tid];
    }
    { WeA_s[tid] = WeUa[tid]; WeB_s[tid] = WeUb[tid]; }
    if (LAST) {
        for (int i = tid; i < 512; i += 64) Wp1_s[i] = Wp1[i];
        if (tid < 16) { bp1_s[tid] = bp1[tid]; Wp2_s[tid] = Wp2[tid]; }
    }
    __syncthreads();

    const int u = blockIdx.x * 64 + tid;
    float in[KIN];
    if (FIRST) {
        in[0] = x_prev[u];
        #pragma unroll
        for (int k = 0; k < 32; ++k) in[1 + k] = agg_ue[u * 32 + k];
    } else {
        #pragma unroll
        for (int k = 0; k < 32; ++k) in[k] = x_prev[u * 32 + k];
        #pragma unroll
        for (int k = 0; k < 32; ++k) in[32 + k] = agg_ue[u * 32 + k];
    }
    float out[32];
    #pragma unroll
    for (int d = 0; d < 32; ++d) {
        float acc = bu_s[d];
        #pragma unroll
        for (int k = 0; k < KIN; ++k) acc = fmaf(in[k], Wu_s[k * 32 + d], acc);
        out[d] = fmaxf(acc, 0.f);
    }
    #pragma unroll
    for (int d = 0; d < 32; ++d) x_new[u * 32 + d] = out[d];
    if (!LAST) {
        #pragma unroll
        for (int d = 0; d < 32; ++d) {
            float acc = bm_s[d];
            #pragma unroll
            for (int k = 0; k < 32; ++k) acc = fmaf(out[k], Wm_s[k * 32 + d], acc);
            Qua_next[u * 32 + d] = acc;
        }
    }
    float r0 = 0.f, r1 = 0.f, s0 = 0.f, s1 = 0.f;
    #pragma unroll
    for (int k = 0; k < 32; ++k) {
        r0 = fmaf(out[k], WeA_s[k * 2],     r0);
        r1 = fmaf(out[k], WeA_s[k * 2 + 1], r1);
        s0 = fmaf(out[k], WeB_s[k * 2],     s0);
        s1 = fmaf(out[k], WeB_s[k * 2 + 1], s1);
    }
    RueA[u] = make_float2(r0, r1);
    RueB[u] = make_float2(s0, s1);
    if (LAST) {
        float z = bp2[0];
        #pragma unroll
        for (int j = 0; j < 16; ++j) {
            float h = bp1_s[j];
            #pragma unroll
            for (int k = 0; k < 32; ++k) h = fmaf(out[k], Wp1_s[k * 16 + j], h);
            z = fmaf(fmaxf(h, 0.f), Wp2_s[j], z);
        }
        float pw = 1.f / (1.f + expf(-z));
        ue_out[u] = make_float2(out[0], pw);
    }
}

// ---------------------------------------------------------------------------
// AP: reduce chunk partials (CA ranges) -> agg_ap, node update, tables
// ---------------------------------------------------------------------------
template<bool FIRST, bool LAST>
__global__ __launch_bounds__(256) void node_ap_kernel(
    const float* __restrict__ partialA, const int* __restrict__ CA,
    const float* __restrict__ x_prev,
    const float* __restrict__ Wu, const float* __restrict__ bu,
    const float* __restrict__ Wm_next, const float* __restrict__ bm_next,
    const float* __restrict__ WeA, const float* __restrict__ beA,
    const float* __restrict__ WeB, const float* __restrict__ beB,
    float* __restrict__ x_new, float* __restrict__ Pau_next,
    float2* __restrict__ RapA, float2* __restrict__ RapB)
{
    __shared__ float red[256];
    __shared__ float agg_s[32];
    __shared__ float xnew_s[32];
    const int a = blockIdx.x, tid = threadIdx.x;
    const int d = tid & 31, p0 = tid >> 5;
    const int c0 = CA[a], c1 = CA[a + 1];
    float acc = 0.f;
    for (int p = c0 + p0; p < c1; p += 8)
        acc += partialA[(size_t)p * 32 + d];
    red[tid] = acc;
    __syncthreads();
    if (tid < 32) {
        float s = 0.f;
        #pragma unroll
        for (int i = 0; i < 8; ++i) s += red[i * 32 + tid];
        agg_s[tid] = s;
    }
    __syncthreads();
    if (tid < 32) {
        float acc2 = bu[d];
        if (FIRST) {
            #pragma unroll
            for (int k = 0; k < 32; ++k) acc2 = fmaf(agg_s[k], Wu[k * 32 + d], acc2);
        } else {
            #pragma unroll
            for (int k = 0; k < 32; ++k) acc2 = fmaf(x_prev[a * 32 + k], Wu[k * 32 + d], acc2);
            #pragma unroll
            for (int k = 0; k < 32; ++k) acc2 = fmaf(agg_s[k], Wu[(32 + k) * 32 + d], acc2);
        }
        float xn = fmaxf(acc2, 0.f);
        xnew_s[d] = xn;
        x_new[a * 32 + d] = xn;
    }
    __syncthreads();
    if (!LAST) {
        if (tid < 32) {
            float acc3 = bm_next[d];
            #pragma unroll
            for (int k = 0; k < 32; ++k) acc3 = fmaf(xnew_s[k], Wm_next[k * 32 + d], acc3);
            Pau_next[a * 32 + d] = acc3;
        }
    }
    if (tid == 0) {
        float q0 = beA[0], q1 = beA[1], t0 = beB[0], t1 = beB[1];
        #pragma unroll
        for (int k = 0; k < 32; ++k) {
            q0 = fmaf(xnew_s[k], WeA[k * 2],     q0);
            q1 = fmaf(xnew_s[k], WeA[k * 2 + 1], q1);
            t0 = fmaf(xnew_s[k], WeB[k * 2],     t0);
            t1 = fmaf(xnew_s[k], WeB[k * 2 + 1], t1);
        }
        RapA[a] = make_float2(q0, q1);
        RapB[a] = make_float2(t0, t1);
    }
}

// ---------------------------------------------------------------------------
extern "C" void kernel_launch(void* const* d_in, const int* in_sizes, int n_in,
                              void* d_out_v, int out_size, void* d_ws, size_t ws_size,
                              hipStream_t stream)
{
    const float*  x_ue   = (const float*)d_in[0];
    const float2* e0ua   = (const float2*)d_in[1];
    const float2* e0au   = (const float2*)d_in[2];
    const int*    src    = (const int*)d_in[3];
    const int*    dst    = (const int*)d_in[4];
    const float* Wm1_ua = (const float*)d_in[5];
    const float* bm1_ua = (const float*)d_in[6];
    const float* Wm1_au = (const float*)d_in[7];
    const float* bm1_au = (const float*)d_in[8];
    const float* Wu1_ap = (const float*)d_in[9];
    const float* bu1_ap = (const float*)d_in[10];
    const float* Wu1_ue = (const float*)d_in[11];
    const float* bu1_ue = (const float*)d_in[12];
    const float* We1_ua = (const float*)d_in[13];
    const float* be1_ua = (const float*)d_in[14];
    const float* We1_au = (const float*)d_in[15];
    const float* be1_au = (const float*)d_in[16];
    const float* Wm_ua  = (const float*)d_in[17];
    const float* bm_ua  = (const float*)d_in[18];
    const float* Wm_au  = (const float*)d_in[19];
    const float* bm_au  = (const float*)d_in[20];
    const float* Wu_ap  = (const float*)d_in[21];
    const float* bu_ap  = (const float*)d_in[22];
    const float* Wu_ue  = (const float*)d_in[23];
    const float* bu_ue  = (const float*)d_in[24];
    const float* We_ua  = (const float*)d_in[25];
    const float* be_ua  = (const float*)d_in[26];
    const float* We_au  = (const float*)d_in[27];
    const float* be_au  = (const float*)d_in[28];
    const float* Wp1    = (const float*)d_in[29];
    const float* bp1    = (const float*)d_in[30];
    const float* Wp2    = (const float*)d_in[31];
    const float* bp2    = (const float*)d_in[32];

    float*  outp    = (float*)d_out_v;
    float2* out_ue  = (float2*)outp;                              // [16384][2]
    float*  out_ap  = outp + N_UE * 2;                            // [128][32]
    float2* out_eua = (float2*)(outp + N_UE * 2 + N_AP * 32);     // [E][2]
    float2* out_eau = (float2*)(outp + N_UE * 2 + N_AP * 32 + (size_t)NE * 2);

    float* ws = (float*)d_ws;
    float* x_ueA  = ws;          ws += N_UE * 32;
    float* x_ueB  = ws;          ws += N_UE * 32;
    float* x_apA  = ws;          ws += N_AP * 32;
    float* x_apB  = ws;          ws += N_AP * 32;
    float* agg_ue = ws;          ws += N_UE * 32;
    float* Qua    = ws;          ws += (N_UE + 1) * 32;
    float* Pau    = ws;          ws += (N_AP + 1) * 32;
    float2* RueA  = (float2*)ws; ws += (N_UE + 2) * 2;
    float2* RueB  = (float2*)ws; ws += (N_UE + 2) * 2;
    float2* RapA  = (float2*)ws; ws += (N_AP + 2) * 2;
    float2* RapB  = (float2*)ws; ws += (N_AP + 2) * 2;
    int* cnt     = (int*)ws;     ws += N_UE;
    int* cntD    = (int*)ws;     ws += N_AP;
    int* CU      = (int*)ws;     ws += N_UE + 4;
    int* histD   = (int*)ws;     ws += NSB * N_AP;
    int* offsD   = (int*)ws;     ws += NSB * N_AP;
    int* CA      = (int*)ws;     ws += N_AP + 4;
    int* cnS     = (int*)ws;     ws += NCHU;
    int* cnD     = (int*)ws;     ws += NCHD_AL;
    int* invS    = (int*)ws;     ws += NE;
    int* invD    = (int*)ws;     ws += NE;
    int4* recS   = (int4*)ws;    ws += (size_t)NEP * 4;           // 35.6 MB
    int* srcD    = (int*)ws;     ws += NEPD;
    float2* attD = (float2*)ws;  ws += (size_t)NEPD * 2;          // 16.8 MB
    float* partialU = ws;        ws += (size_t)NCHU * 32;         // 35.6 MB
    float* partialA = ws;        ws += (size_t)NCHD_AL * 32;      // 16.8 MB
    unsigned short* histS = (unsigned short*)partialU;            // 8 MB alias
    unsigned short* baseS = (unsigned short*)(partialU + (size_t)(NSB * N_UE / 2)); // 8 MB alias

    dim3 blk(256);

    // ---- sort structure (no prefill; sentinels in build_map) ----
    hist_both<<<NSB, blk, 0, stream>>>(src, dst, histS, histD);
    colscan_kernel<<<N_UE / 256, blk, 0, stream>>>(histS, baseS, cnt);
    scan_src<<<1, blk, 0, stream>>>(cnt, CU);
    scan_dst<<<1, dim3(128), 0, stream>>>(histD, offsD, CA, cntD);
    scatter_both<<<NSB, blk, 0, stream>>>(src, dst, e0ua, e0au, baseS, CU, offsD,
                                          recS, invS, srcD, attD, invD);
    build_map_src<<<N_UE / 256, blk, 0, stream>>>(CU, cnt, cnS, recS);
    build_map_dst<<<1, dim3(128), 0, stream>>>(CA, cntD, cnD, srcD);

    init_kernel<<<N_UE * 32 / 256, blk, 0, stream>>>(x_ue, Wm1_ua, bm1_ua, bm1_au, Qua, Pau);

    const int PB = SRC_BLKS + DST_BLKS;

    // ---- layer 1 ----
    pass_both<false><<<PB, blk, 0, stream>>>(
        cnS, recS, cnD, srcD, attD,
        nullptr, nullptr, nullptr, nullptr, nullptr, nullptr,
        Qua, Pau, Wm1_ua + 32, Wm1_au, partialU, partialA);
    reduce_ue<<<N_UE * 32 / 256, blk, 0, stream>>>(CU, partialU, agg_ue);
    node_ue_kernel<true, false><<<N_UE / 64, dim3(64), 0, stream>>>(
        x_ue, agg_ue, Wu1_ue, bu1_ue, Wm_ua, bm_ua, We1_ua, We1_au,
        nullptr, nullptr, nullptr, nullptr,
        x_ueA, Qua, RueA, RueB, nullptr);
    node_ap_kernel<true, false><<<N_AP, blk, 0, stream>>>(
        partialA, CA, nullptr, Wu1_ap, bu1_ap, Wm_au, bm_au,
        We1_ua + 64, be1_ua, We1_au + 64, be1_au,
        x_apA, Pau, RapA, RapB);

    // ---- layer 2 (edge-update 1 fused) ----
    pass_both<true><<<PB, blk, 0, stream>>>(
        cnS, recS, cnD, srcD, attD,
        RueA, RueB, RapA, RapB, We1_ua + 128, We1_au + 128,
        Qua, Pau, Wm_ua + 1024, Wm_au + 1024, partialU, partialA);
    reduce_ue<<<N_UE * 32 / 256, blk, 0, stream>>>(CU, partialU, agg_ue);
    node_ue_kernel<false, false><<<N_UE / 64, dim3(64), 0, stream>>>(
        x_ueA, agg_ue, Wu_ue, bu_ue, Wm_ua + 1088, bm_ua + 32, We_ua, We_au,
        nullptr, nullptr, nullptr, nullptr,
        x_ueB, Qua, RueA, RueB, nullptr);
    node_ap_kernel<false, false><<<N_AP, blk, 0, stream>>>(
        partialA, CA, x_apA, Wu_ap, bu_ap, Wm_au + 1088, bm_au + 32,
        We_ua + 64, be_ua, We_au + 64, be_au,
        x_apB, Pau, RapA, RapB);

    // ---- layer 3 (edge-update 2 fused) ----
    pass_both<true><<<PB, blk, 0, stream>>>(
        cnS, recS, cnD, srcD, attD,
        RueA, RueB, RapA, RapB, We_ua + 128, We_au + 128,
        Qua, Pau, Wm_ua + 2112, Wm_au + 2112, partialU, partialA);
    reduce_ue<<<N_UE * 32 / 256, blk, 0, stream>>>(CU, partialU, agg_ue);
    node_ue_kernel<false, false><<<N_UE / 64, dim3(64), 0, stream>>>(
        x_ueB, agg_ue, Wu_ue + 2048, bu_ue + 32, Wm_ua + 2176, bm_ua + 64,
        We_ua + 132, We_au + 132,
        nullptr, nullptr, nullptr, nullptr,
        x_ueA, Qua, RueA, RueB, nullptr);
    node_ap_kernel<false, false><<<N_AP, blk, 0, stream>>>(
        partialA, CA, x_apB, Wu_ap + 2048, bu_ap + 32, Wm_au + 2176, bm_au + 64,
        We_ua + 196, be_ua + 2, We_au + 196, be_au + 2,
        x_apA, Pau, RapA, RapB);

    // ---- layer 4 (edge-update 3 fused) ----
    pass_both<true><<<PB, blk, 0, stream>>>(
        cnS, recS, cnD, srcD, attD,
        RueA, RueB, RapA, RapB, We_ua + 260, We_au + 260,
        Qua, Pau, Wm_ua + 3200, Wm_au + 3200, partialU, partialA);
    reduce_ue<<<N_UE * 32 / 256, blk, 0, stream>>>(CU, partialU, agg_ue);
    node_ue_kernel<false, true><<<N_UE / 64, dim3(64), 0, stream>>>(
        x_ueA, agg_ue, Wu_ue + 4096, bu_ue + 64, nullptr, nullptr,
        We_ua + 264, We_au + 264,
        Wp1, bp1, Wp2, bp2,
        x_ueB, nullptr, RueA, RueB, out_ue);
    node_ap_kernel<false, true><<<N_AP, blk, 0, stream>>>(
        partialA, CA, x_apA, Wu_ap + 4096, bu_ap + 64, nullptr, nullptr,
        We_ua + 328, be_ua + 4, We_au + 328, be_au + 4,
        out_ap, nullptr, RapA, RapB);

    // ---- final edge update (layer 4), original order ----
    final_edge<<<NE / 256, blk, 0, stream>>>(
        src, dst, invS, invD, recS, attD,
        RueA, RueB, RapA, RapB,
        We_ua + 392, We_au + 392, out_eua, out_eau);
}